// Round 10
// baseline (1081.519 us; speedup 1.0000x reference)
//
#include <hip/hip_runtime.h>
#include <hip/hip_bf16.h>
#include <cmath>

#define NN      25000
#define NEDGE   400000
#define NBATCH  64
#define IN_DIM  16
#define HID     128
#define OUT_DIM 16
#define EDGE_DIM 16
#define TDIM    64
#define NL      4
#define EIN     273
#define EPB     64            // edges per block (MFMA edge kernel)
#define W2KB    16            // k-blocks for 128-K GEMMs
#define A_PAD   65            // e-dimension pad for LDS A tiles
#define A3OFF   (16*A_PAD*8)  // A3 region offset (elements) inside sA
#define NPB     32            // nodes per block (node kernel)
#define NPAD    33            // e-pad for node kernel

typedef short bfrag __attribute__((ext_vector_type(8)));
typedef float ffrag __attribute__((ext_vector_type(4)));

// fast silu/sigmoid: v_exp + v_rcp (approx, ~1e-6 rel err) instead of the
// precise-division sequence (saves ~5 VALU ops per call; ~80 calls/thread in edge)
__device__ __forceinline__ float siluf(float v) { return v * __builtin_amdgcn_rcpf(1.f + __expf(-v)); }
__device__ __forceinline__ float sigm(float v)  { return __builtin_amdgcn_rcpf(1.f + __expf(-v)); }
__device__ __forceinline__ unsigned short f2b(float f) {
    unsigned u = __float_as_uint(f);
    u = (u + 0x7FFFu + ((u >> 16) & 1u)) >> 16;
    return (unsigned short)u;
}
__device__ __forceinline__ float b2f(unsigned short b) {
    return __uint_as_float(((unsigned)b) << 16);
}
// interleaved column map: slot n' holds feature ileave(n') so that thread
// (w,colid) owns adjacent features f0=w*32+2*colid (nt=0), f0+1 (nt=1)
__device__ __forceinline__ int ileave(int n) {
    return (n & 0x60) | ((n & 15) << 1) | ((n >> 4) & 1);
}

// ================= sort prep =================
__global__ __launch_bounds__(256) void hist_kernel(const int* __restrict__ row, int* __restrict__ deg) {
    const int tid = blockIdx.x * 256 + threadIdx.x;
    if (tid < NEDGE) atomicAdd(&deg[row[tid]], 1);
}

__global__ __launch_bounds__(1024) void scan_kernel(const int* __restrict__ deg, int* __restrict__ row_start) {
    __shared__ int part[1024];
    const int tid = threadIdx.x;
    const int base = tid * 25;
    int sum = 0;
    for (int i = 0; i < 25; i++) { const int idx = base + i; if (idx < NN) sum += deg[idx]; }
    part[tid] = sum;
    __syncthreads();
    for (int off = 1; off < 1024; off <<= 1) {
        int v = (tid >= off) ? part[tid - off] : 0;
        __syncthreads();
        part[tid] += v;
        __syncthreads();
    }
    int run = part[tid] - sum;
    for (int i = 0; i < 25; i++) {
        const int idx = base + i;
        if (idx < NN) { row_start[idx] = run; run += deg[idx]; }
    }
    if (tid == 1023) row_start[NN] = part[1023];
}

__global__ __launch_bounds__(256) void scatter_kernel(
    const int* __restrict__ row, const int* __restrict__ col,
    const int* __restrict__ row_start, int* __restrict__ cursor,
    int* __restrict__ rowp, int* __restrict__ colp, int* __restrict__ eorder)
{
    const int tid = blockIdx.x * 256 + threadIdx.x;
    if (tid >= NEDGE) return;
    const int r = row[tid];
    const int pos = row_start[r] + atomicAdd(&cursor[r], 1);
    rowp[pos] = r; colp[pos] = col[tid]; eorder[pos] = tid;
}

__global__ __launch_bounds__(256) void ea_pack(
    const float* __restrict__ ea, const int* __restrict__ eorder, unsigned short* __restrict__ eabp)
{
    const int tid = blockIdx.x * 256 + threadIdx.x;
    if (tid >= NEDGE) return;
    const int e = eorder[tid];
    const float4* src = (const float4*)&ea[(size_t)e * 16];
    bfrag o0, o1;
    #pragma unroll
    for (int q = 0; q < 2; q++) {
        const float4 a = src[q];
        o0[q*4+0] = (short)f2b(a.x); o0[q*4+1] = (short)f2b(a.y);
        o0[q*4+2] = (short)f2b(a.z); o0[q*4+3] = (short)f2b(a.w);
    }
    #pragma unroll
    for (int q = 0; q < 2; q++) {
        const float4 a = src[2+q];
        o1[q*4+0] = (short)f2b(a.x); o1[q*4+1] = (short)f2b(a.y);
        o1[q*4+2] = (short)f2b(a.z); o1[q*4+3] = (short)f2b(a.w);
    }
    *(bfrag*)&eabp[(size_t)tid * 16]     = o0;
    *(bfrag*)&eabp[(size_t)tid * 16 + 8] = o1;
}

// ================= prep: edge weights =================
__global__ __launch_bounds__(256) void prep_w(
    const float* __restrict__ ew1, const float* __restrict__ ew2, const float* __restrict__ cw1,
    unsigned short* __restrict__ w1x, unsigned short* __restrict__ w1rp,
    unsigned short* __restrict__ w1cp, unsigned short* __restrict__ w2p,
    unsigned short* __restrict__ c1p)
{
    const int PER_L = 68 * 128;  // 4 + 16 + 16 + 16 + 16 kblocks
    int tid = blockIdx.x * 256 + threadIdx.x;
    if (tid >= NL * PER_L) return;
    const int l = tid / PER_L, rem = tid % PER_L;
    const int kb = rem >> 7, n = rem & 127;
    unsigned short o[8];
    const float* W1 = ew1 + (size_t)l * EIN * HID;
    if (kb < 4) {
        const int nc = ileave(n);
        #pragma unroll
        for (int j = 0; j < 8; j++) {
            const int kk = kb * 8 + j;
            const int ok = (kk < 16) ? (257 + kk) : (kk == 16 ? 256 : -1);
            o[j] = (ok >= 0) ? f2b(W1[(size_t)ok * HID + nc]) : (unsigned short)0;
        }
        #pragma unroll
        for (int j = 0; j < 8; j++) w1x[(((size_t)l * 4 + kb) * 128 + n) * 8 + j] = o[j];
    } else if (kb < 20) {
        const int kb2 = kb - 4;
        const int nc = ileave(n);
        #pragma unroll
        for (int j = 0; j < 8; j++) o[j] = f2b(W1[(size_t)(kb2 * 8 + j) * HID + nc]);
        #pragma unroll
        for (int j = 0; j < 8; j++) w1rp[(((size_t)l * 16 + kb2) * 128 + n) * 8 + j] = o[j];
    } else if (kb < 36) {
        const int kb2 = kb - 20;
        const int nc = ileave(n);
        #pragma unroll
        for (int j = 0; j < 8; j++) o[j] = f2b(W1[(size_t)(128 + kb2 * 8 + j) * HID + nc]);
        #pragma unroll
        for (int j = 0; j < 8; j++) w1cp[(((size_t)l * 16 + kb2) * 128 + n) * 8 + j] = o[j];
    } else if (kb < 52) {
        const int kb2 = kb - 36;
        const float* W = ew2 + (size_t)l * HID * HID;
        const int nc = ileave(n);
        #pragma unroll
        for (int j = 0; j < 8; j++) o[j] = f2b(W[(size_t)(kb2 * 8 + j) * HID + nc]);
        #pragma unroll
        for (int j = 0; j < 8; j++) w2p[(((size_t)l * W2KB + kb2) * 128 + n) * 8 + j] = o[j];
    } else {
        const int kb2 = kb - 52;
        const float* W = cw1 + (size_t)l * HID * HID;
        #pragma unroll
        for (int j = 0; j < 8; j++) o[j] = f2b(W[(size_t)(kb2 * 8 + j) * HID + n]);
        #pragma unroll
        for (int j = 0; j < 8; j++) c1p[(((size_t)l * W2KB + kb2) * 128 + n) * 8 + j] = o[j];
    }
}

// ================= prep: node/out weights =================
__global__ __launch_bounds__(256) void prep_w2(
    const float* __restrict__ nw1, const float* __restrict__ nw2,
    const float* __restrict__ ow1, const float* __restrict__ ow2,
    unsigned short* __restrict__ n1p, unsigned short* __restrict__ n2p,
    unsigned short* __restrict__ o1p, unsigned short* __restrict__ o2p)
{
    const int C1 = NL * 32 * 128;
    const int C2 = C1 + NL * 16 * 128;
    const int C3 = C2 + 16 * 128;
    const int C4 = C3 + 16 * 16;
    int tid = blockIdx.x * 256 + threadIdx.x;
    if (tid >= C4) return;
    if (tid < C1) {
        const int l = tid / (32*128), rem = tid % (32*128);
        const int kb = rem >> 7, n = rem & 127;
        const int nc = ileave(n);
        #pragma unroll
        for (int j = 0; j < 8; j++)
            n1p[(size_t)tid*8 + j] = f2b(nw1[((size_t)l*256 + kb*8 + j)*128 + nc]);
    } else if (tid < C2) {
        const int t2 = tid - C1;
        const int l = t2 / (16*128), rem = t2 % (16*128);
        const int kb = rem >> 7, n = rem & 127;
        const int nc = ileave(n);
        #pragma unroll
        for (int j = 0; j < 8; j++)
            n2p[(size_t)t2*8 + j] = f2b(nw2[((size_t)l*128 + kb*8 + j)*128 + nc]);
    } else if (tid < C3) {
        const int t2 = tid - C2;
        const int kb = t2 >> 7, n = t2 & 127;
        #pragma unroll
        for (int j = 0; j < 8; j++)
            o1p[(size_t)t2*8 + j] = f2b(ow1[(size_t)(kb*8 + j)*128 + n]);
    } else {
        const int t2 = tid - C3;
        const int kb = t2 >> 4, n = t2 & 15;
        #pragma unroll
        for (int j = 0; j < 8; j++)
            o2p[(size_t)t2*8 + j] = f2b(ow2[(size_t)(kb*8 + j)*16 + n]);
    }
}

// ================= time embedding =================
__global__ __launch_bounds__(HID) void te_kernel(
    const float* __restrict__ t, const float* __restrict__ tw1, const float* __restrict__ tb1,
    const float* __restrict__ tw2, const float* __restrict__ tb2, float* __restrict__ te_out)
{
    __shared__ float s0[TDIM];
    __shared__ float s1[HID];
    const int b = blockIdx.x, j = threadIdx.x;
    const float tv = t[b];
    if (j < TDIM) {
        const int k = j & 31;
        const float freq = expf((float)k * (-logf(10000.f) / 31.f));
        const float a = tv * freq;
        s0[j] = (j < 32) ? sinf(a) : cosf(a);
    }
    __syncthreads();
    float acc = tb1[j];
    for (int k = 0; k < TDIM; k++) acc += s0[k] * tw1[k*HID + j];
    s1[j] = siluf(acc);
    __syncthreads();
    float acc2 = tb2[j];
    for (int k = 0; k < HID; k++) acc2 += s1[k] * tw2[k*HID + j];
    te_out[b*HID + j] = acc2;
}

// ================= node embedding: 2 nodes/block; zeroes m_i for layer 0 =================
__global__ __launch_bounds__(256) void embed_kernel(
    const float* __restrict__ h_in, const float* __restrict__ x_in,
    const int* __restrict__ batch,
    const float* __restrict__ node_w, const float* __restrict__ node_b,
    const float* __restrict__ te, float* __restrict__ h, unsigned short* __restrict__ hbf,
    float* __restrict__ x0, float* __restrict__ m_i)
{
    __shared__ float hs[2][IN_DIM];
    const int local = threadIdx.x >> 7;
    const int j = threadIdx.x & 127;
    const int n = blockIdx.x * 2 + local;
    if (j < IN_DIM) hs[local][j] = h_in[n*IN_DIM + j];
    if (j >= 64 && j < 67) x0[n*3 + (j - 64)] = x_in[n*3 + (j - 64)];
    __syncthreads();
    float acc = node_b[j];
    #pragma unroll
    for (int k = 0; k < IN_DIM; k++) acc += hs[local][k] * node_w[k*HID + j];
    acc += te[batch[n]*HID + j];
    h[(size_t)n*HID + j]   = acc;
    hbf[(size_t)n*HID + j] = f2b(acc);
    m_i[(size_t)n*HID + j] = 0.f;
}

// ================= per-layer precompute: P = h@W1row, Q = h@W1col (fp32 out) =================
__global__ __launch_bounds__(256) void pq_kernel(
    const unsigned short* __restrict__ hbf,
    const unsigned short* __restrict__ Wr, const unsigned short* __restrict__ Wc,
    float* __restrict__ P, float* __restrict__ Q)
{
    __shared__ unsigned short sA[16 * A_PAD * 8];
    const int t = threadIdx.x, lane = t & 63, w = t >> 6;
    const int quad = lane >> 4, colid = lane & 15;
    const int n0 = blockIdx.x * 64;

    #pragma unroll
    for (int it = 0; it < 4; it++) {
        const int c = t + it * 256;
        const int e = c >> 4, kb = c & 15;
        const int nidx = min(n0 + e, NN - 1);
        *(bfrag*)&sA[(kb*A_PAD + e) * 8] = *(const bfrag*)&hbf[(size_t)nidx * HID + kb * 8];
    }
    __syncthreads();

    ffrag aP[4][2] = {}, aQ[4][2] = {};
    for (int ks = 0; ks < 4; ks++) {
        const int kb = ks * 4 + quad;
        const bfrag p0 = *(const bfrag*)&Wr[((size_t)kb * 128 + w*32 + colid) * 8];
        const bfrag p1 = *(const bfrag*)&Wr[((size_t)kb * 128 + w*32 + 16 + colid) * 8];
        const bfrag q0 = *(const bfrag*)&Wc[((size_t)kb * 128 + w*32 + colid) * 8];
        const bfrag q1 = *(const bfrag*)&Wc[((size_t)kb * 128 + w*32 + 16 + colid) * 8];
        #pragma unroll
        for (int mt = 0; mt < 4; mt++) {
            const bfrag a = *(const bfrag*)&sA[(kb*A_PAD + mt*16 + colid) * 8];
            aP[mt][0] = __builtin_amdgcn_mfma_f32_16x16x32_bf16(a, p0, aP[mt][0], 0, 0, 0);
            aP[mt][1] = __builtin_amdgcn_mfma_f32_16x16x32_bf16(a, p1, aP[mt][1], 0, 0, 0);
            aQ[mt][0] = __builtin_amdgcn_mfma_f32_16x16x32_bf16(a, q0, aQ[mt][0], 0, 0, 0);
            aQ[mt][1] = __builtin_amdgcn_mfma_f32_16x16x32_bf16(a, q1, aQ[mt][1], 0, 0, 0);
        }
    }
    const int f0 = w*32 + 2*colid;
    #pragma unroll
    for (int mt = 0; mt < 4; mt++)
        #pragma unroll
        for (int reg = 0; reg < 4; reg++) {
            const int n = n0 + mt*16 + quad*4 + reg;
            if (n < NN) {
                *(float2*)&P[(size_t)n*HID + f0] = make_float2(aP[mt][0][reg], aP[mt][1][reg]);
                *(float2*)&Q[(size_t)n*HID + f0] = make_float2(aQ[mt][0][reg], aQ[mt][1][reg]);
            }
        }
}

// ================= fused MFMA edge kernel (row-sorted edges) =================
__global__ __launch_bounds__(256) void edge_mfma(
    const float* __restrict__ P, const float* __restrict__ Q,
    const float* __restrict__ x,
    float* __restrict__ x_new, float* __restrict__ m_i,
    const int* __restrict__ rowp, const int* __restrict__ colp,
    const unsigned short* __restrict__ eabp,
    const unsigned short* __restrict__ W1X, const float* __restrict__ B1,
    const unsigned short* __restrict__ W2p, const float* __restrict__ B2,
    const unsigned short* __restrict__ C1p, const float* __restrict__ CB1,
    const float* __restrict__ AW, const float* __restrict__ ABv,
    const float* __restrict__ CW2)
{
    __shared__ unsigned short sA[32 * A_PAD * 8];  // A2 = kb0..15; A3 at A3OFF (Aea aliases A3 start)
    __shared__ int rc[EPB][2];
    __shared__ float AWs[HID];
    float* scr  = (float*)sA;       // aliases dead A2 region during epilogues
    float* attS = scr;              // [64]
    float* pscr = scr;              // [64 k][66] coord partials; alive only after final sync

    const int t = threadIdx.x;
    const int e0 = blockIdx.x * EPB;
    const int lane = t & 63, w = t >> 6;
    const int quad = lane >> 4, colid = lane & 15;
    const int f0 = w*32 + 2*colid;

    // ---- stage: rc, coord-diff, ea + radial into Aea (A3 region), AW ----
    float cd0 = 0.f, cd1 = 0.f, cd2 = 0.f;
    if (t < EPB) {
        const int r = rowp[e0 + t], c = colp[e0 + t];
        rc[t][0] = r; rc[t][1] = c;
        const float dx = x[r*3+0] - x[c*3+0];
        const float dy = x[r*3+1] - x[c*3+1];
        const float dz = x[r*3+2] - x[c*3+2];
        const float rad = dx*dx + dy*dy + dz*dz;
        const float inv = 1.f / sqrtf(rad + 1e-8f);
        cd0 = dx*inv; cd1 = dy*inv; cd2 = dz*inv;
        unsigned short* p2 = &sA[A3OFF + (2*A_PAD + t) * 8];   // Aea kb2: [radial, 0..]
        p2[0] = f2b(rad);
        #pragma unroll
        for (int j = 1; j < 8; j++) p2[j] = 0;
        unsigned short* p3 = &sA[A3OFF + (3*A_PAD + t) * 8];   // Aea kb3: zeros
        #pragma unroll
        for (int j = 0; j < 8; j++) p3[j] = 0;
    }
    if (t >= 128 && t < 256) AWs[t - 128] = AW[t - 128];
    if (t < 128) {
        const int e = t >> 1, hh = t & 1;
        *(bfrag*)&sA[A3OFF + (hh*A_PAD + e) * 8] = *(const bfrag*)&eabp[(size_t)(e0 + e) * 16 + hh * 8];
    }
    __syncthreads();

    // ---- GEMM_ea: [64 x 32] @ [32 x 128] (K=32: ea|radial), bias B1 preloaded ----
    ffrag accea[4][2];
    {
        const float b0v = B1[f0], b1v = B1[f0+1];
        #pragma unroll
        for (int mt = 0; mt < 4; mt++)
            #pragma unroll
            for (int r = 0; r < 4; r++) { accea[mt][0][r] = b0v; accea[mt][1][r] = b1v; }
    }
    {
        const bfrag eb0 = *(const bfrag*)&W1X[((size_t)quad * 128 + w*32 + colid) * 8];
        const bfrag eb1 = *(const bfrag*)&W1X[((size_t)quad * 128 + w*32 + 16 + colid) * 8];
        #pragma unroll
        for (int mt = 0; mt < 4; mt++) {
            const bfrag a = *(const bfrag*)&sA[A3OFF + (quad*A_PAD + mt*16 + colid) * 8];
            accea[mt][0] = __builtin_amdgcn_mfma_f32_16x16x32_bf16(a, eb0, accea[mt][0], 0, 0, 0);
            accea[mt][1] = __builtin_amdgcn_mfma_f32_16x16x32_bf16(a, eb1, accea[mt][1], 0, 0, 0);
        }
    }

    // ---- epilogue 1: m1 = silu(P[row] + Q[col] + ea_part), packed bf16x2 -> A2 ----
    {
        const int kb = f0 >> 3, j = f0 & 7;
        #pragma unroll
        for (int mt = 0; mt < 4; mt++) {
            float2 pv[4], qv[4];
            #pragma unroll
            for (int reg = 0; reg < 4; reg++) {
                const int e = mt*16 + quad*4 + reg;
                pv[reg] = *(const float2*)&P[(size_t)rc[e][0]*HID + f0];
                qv[reg] = *(const float2*)&Q[(size_t)rc[e][1]*HID + f0];
            }
            #pragma unroll
            for (int reg = 0; reg < 4; reg++) {
                const int e = mt*16 + quad*4 + reg;
                const float v0 = siluf(pv[reg].x + qv[reg].x + accea[mt][0][reg]);
                const float v1 = siluf(pv[reg].y + qv[reg].y + accea[mt][1][reg]);
                *(__hip_bfloat162*)&sA[(kb*A_PAD + e) * 8 + j] =
                    __float22bfloat162_rn(make_float2(v0, v1));   // A2
            }
        }
    }
    __syncthreads();

    // ---- GEMM2: [64 x 128] @ [128 x 128] (interleaved columns) ----
    ffrag acc2[4][2] = {};
    for (int ks = 0; ks < 4; ks++) {
        const int kb = ks * 4 + quad;
        const bfrag b0 = *(const bfrag*)&W2p[((size_t)kb * 128 + w*32 + colid) * 8];
        const bfrag b1 = *(const bfrag*)&W2p[((size_t)kb * 128 + w*32 + 16 + colid) * 8];
        #pragma unroll
        for (int mt = 0; mt < 4; mt++) {
            const bfrag a = *(const bfrag*)&sA[(kb*A_PAD + mt*16 + colid) * 8];
            acc2[mt][0] = __builtin_amdgcn_mfma_f32_16x16x32_bf16(a, b0, acc2[mt][0], 0, 0, 0);
            acc2[mt][1] = __builtin_amdgcn_mfma_f32_16x16x32_bf16(a, b1, acc2[mt][1], 0, 0, 0);
        }
    }
    // ---- epilogue 2: silu -> packed bf16x2 UNSCALED m2 into A3 ----
    {
        const int kb = f0 >> 3, j = f0 & 7;
        const float b0v = B2[f0], b1v = B2[f0+1];
        #pragma unroll
        for (int mt = 0; mt < 4; mt++)
            #pragma unroll
            for (int reg = 0; reg < 4; reg++) {
                const float v0 = siluf(acc2[mt][0][reg] + b0v);
                const float v1 = siluf(acc2[mt][1][reg] + b1v);
                const int e = mt*16 + quad*4 + reg;
                *(__hip_bfloat162*)&sA[A3OFF + (kb*A_PAD + e) * 8 + j] =
                    __float22bfloat162_rn(make_float2(v0, v1));
            }
    }
    __syncthreads();   // A3 visible; A2 dead (scr region safe)

    // ---- attention: att[e] = sigmoid(m2[e] . AW + ab) ----
    {
        const int e = t >> 2, q = t & 3;
        float s = 0.f;
        #pragma unroll
        for (int kk = 0; kk < 4; kk++) {
            const int kb = q*4 + kk;
            const bfrag v = *(const bfrag*)&sA[A3OFF + (kb*A_PAD + e) * 8];
            #pragma unroll
            for (int j = 0; j < 8; j++) s += b2f((unsigned short)v[j]) * AWs[kb*8 + j];
        }
        s += __shfl_xor(s, 1);
        s += __shfl_xor(s, 2);
        if (q == 0) attS[e] = sigm(s + ABv[0]);
    }
    __syncthreads();

    // ---- GEMM3 on UNSCALED m2: [64 x 128] @ CW1 [128 x 128] (canonical cols) ----
    ffrag acc3[4][2] = {};
    for (int ks = 0; ks < 4; ks++) {
        const int kb = ks * 4 + quad;
        const bfrag b0 = *(const bfrag*)&C1p[((size_t)kb * 128 + w*32 + colid) * 8];
        const bfrag b1 = *(const bfrag*)&C1p[((size_t)kb * 128 + w*32 + 16 + colid) * 8];
        #pragma unroll
        for (int mt = 0; mt < 4; mt++) {
            const bfrag a = *(const bfrag*)&sA[A3OFF + (kb*A_PAD + mt*16 + colid) * 8];
            acc3[mt][0] = __builtin_amdgcn_mfma_f32_16x16x32_bf16(a, b0, acc3[mt][0], 0, 0, 0);
            acc3[mt][1] = __builtin_amdgcn_mfma_f32_16x16x32_bf16(a, b1, acc3[mt][1], 0, 0, 0);
        }
    }

    // ---- m_i segmented reduction: READ-ONLY, scaled on the fly ----
    {
        const int fkb0 = lane >> 3,     fj = lane & 7;     // f = lane
        const int fkb1 = 8 + (lane >> 3);                   // f = lane + 64
        float a0 = 0.f, a1 = 0.f;
        for (int i = 0; i < 16; i++) {
            const int e = (w << 4) + i;
            const float av = attS[e];
            const int r = rc[e][0];
            a0 += b2f(sA[A3OFF + (fkb0*A_PAD + e) * 8 + fj]) * av;
            a1 += b2f(sA[A3OFF + (fkb1*A_PAD + e) * 8 + fj]) * av;
            const bool flush = (i == 15) || (rc[e+1][0] != r);
            if (flush) {
                atomicAdd(&m_i[(size_t)r * HID + lane],      a0);
                atomicAdd(&m_i[(size_t)r * HID + lane + 64], a1);
                a0 = 0.f; a1 = 0.f;
            }
        }
    }

    // ---- GEMM3 epilogue: att applied here (row-scaling commutes), coord partials ----
    float p[4][4];
    {
        const float cb0v = CB1[w*32 + colid], cb1v = CB1[w*32 + 16 + colid];
        const float cwv0 = CW2[w*32 + colid], cwv1 = CW2[w*32 + 16 + colid];
        #pragma unroll
        for (int mt = 0; mt < 4; mt++) {
            const float4 a4 = *(const float4*)&attS[mt*16 + quad*4];
            const float att_r[4] = {a4.x, a4.y, a4.z, a4.w};
            #pragma unroll
            for (int reg = 0; reg < 4; reg++)
                p[mt][reg] = siluf(att_r[reg] * acc3[mt][0][reg] + cb0v) * cwv0
                           + siluf(att_r[reg] * acc3[mt][1][reg] + cb1v) * cwv1;
        }
    }
    __syncthreads();   // all A3/attS reads done; pscr may now overwrite A2/A3
    // scatter: pscr[k][e] stride 66 (write banks ~2-way, read banks conflict-free)
    {
        const int k = w*16 + colid;
        #pragma unroll
        for (int mt = 0; mt < 4; mt++)
            #pragma unroll
            for (int rr = 0; rr < 2; rr++) {
                const int e = mt*16 + quad*4 + rr*2;
                *(float2*)&pscr[k*66 + e] = make_float2(p[mt][rr*2], p[mt][rr*2+1]);
            }
    }
    __syncthreads();
    if (t < EPB) {
        float s = 0.f;
        #pragma unroll
        for (int k2 = 0; k2 < 64; k2++) s += pscr[k2*66 + t];
        const int r = rc[t][0];
        atomicAdd(&x_new[r*3+0], cd0 * s);
        atomicAdd(&x_new[r*3+1], cd1 * s);
        atomicAdd(&x_new[r*3+2], cd2 * s);
    }
}

// ================= MFMA node MLP + residual + layernorm (32 nodes/block); zeroes m_i =================
__global__ __launch_bounds__(256) void node_mfma(
    float* __restrict__ h, unsigned short* __restrict__ hbf, float* __restrict__ m_i,
    const unsigned short* __restrict__ N1p, const float* __restrict__ NB1,
    const unsigned short* __restrict__ N2p, const float* __restrict__ NB2,
    const float* __restrict__ LG, const float* __restrict__ LB)
{
    __shared__ unsigned short sA[32 * NPAD * 8];
    __shared__ float mu_s[NPB], rs_s[NPB];
    float* hres = (float*)sA;                       // [32][130] fp32

    const int t = threadIdx.x, lane = t & 63, w = t >> 6;
    const int quad = lane >> 4, colid = lane & 15;
    const int n0 = blockIdx.x * NPB;

    #pragma unroll
    for (int it = 0; it < 2; it++) {
        const int c = t + it * 256;
        const int e = c >> 4, kb = c & 15;
        const int nidx = min(n0 + e, NN - 1);
        *(bfrag*)&sA[(kb*NPAD + e) * 8] = *(const bfrag*)&hbf[(size_t)nidx * HID + kb * 8];
    }
    #pragma unroll
    for (int it = 0; it < 2; it++) {
        const int c = t + it * 256;
        const int e = c >> 4, kb = c & 15;
        const int nidx = min(n0 + e, NN - 1);
        const float4 v0 = *(const float4*)&m_i[(size_t)nidx * HID + kb * 8];
        const float4 v1 = *(const float4*)&m_i[(size_t)nidx * HID + kb * 8 + 4];
        bfrag bv;
        bv[0]=(short)f2b(v0.x); bv[1]=(short)f2b(v0.y); bv[2]=(short)f2b(v0.z); bv[3]=(short)f2b(v0.w);
        bv[4]=(short)f2b(v1.x); bv[5]=(short)f2b(v1.y); bv[6]=(short)f2b(v1.z); bv[7]=(short)f2b(v1.w);
        *(bfrag*)&sA[((16 + kb)*NPAD + e) * 8] = bv;
        if (n0 + e < NN) {
            const float4 z4 = {0.f, 0.f, 0.f, 0.f};
            *(float4*)&m_i[(size_t)nidx * HID + kb * 8]     = z4;
            *(float4*)&m_i[(size_t)nidx * HID + kb * 8 + 4] = z4;
        }
    }
    __syncthreads();

    const int f0 = w*32 + 2*colid;
    ffrag acc1[2][2];
    {
        const float b0v = NB1[f0], b1v = NB1[f0+1];
        #pragma unroll
        for (int mt = 0; mt < 2; mt++)
            #pragma unroll
            for (int r = 0; r < 4; r++) { acc1[mt][0][r] = b0v; acc1[mt][1][r] = b1v; }
    }
    for (int ks = 0; ks < 8; ks++) {
        const int kb = ks * 4 + quad;
        const bfrag b0 = *(const bfrag*)&N1p[((size_t)kb * 128 + w*32 + colid) * 8];
        const bfrag b1 = *(const bfrag*)&N1p[((size_t)kb * 128 + w*32 + 16 + colid) * 8];
        #pragma unroll
        for (int mt = 0; mt < 2; mt++) {
            const bfrag a = *(const bfrag*)&sA[(kb*NPAD + mt*16 + colid) * 8];
            acc1[mt][0] = __builtin_amdgcn_mfma_f32_16x16x32_bf16(a, b0, acc1[mt][0], 0, 0, 0);
            acc1[mt][1] = __builtin_amdgcn_mfma_f32_16x16x32_bf16(a, b1, acc1[mt][1], 0, 0, 0);
        }
    }
    __syncthreads();
    {
        const int kb = f0 >> 3, j = f0 & 7;
        #pragma unroll
        for (int mt = 0; mt < 2; mt++)
            #pragma unroll
            for (int reg = 0; reg < 4; reg++) {
                const float v0 = siluf(acc1[mt][0][reg]);
                const float v1 = siluf(acc1[mt][1][reg]);
                const int e = mt*16 + quad*4 + reg;
                *(__hip_bfloat162*)&sA[(kb*NPAD + e) * 8 + j] =
                    __float22bfloat162_rn(make_float2(v0, v1));
            }
    }
    __syncthreads();

    ffrag acc2[2][2];
    {
        const float b0v = NB2[f0], b1v = NB2[f0+1];
        #pragma unroll
        for (int mt = 0; mt < 2; mt++)
            #pragma unroll
            for (int r = 0; r < 4; r++) { acc2[mt][0][r] = b0v; acc2[mt][1][r] = b1v; }
    }
    for (int ks = 0; ks < 4; ks++) {
        const int kb = ks * 4 + quad;
        const bfrag b0 = *(const bfrag*)&N2p[((size_t)kb * 128 + w*32 + colid) * 8];
        const bfrag b1 = *(const bfrag*)&N2p[((size_t)kb * 128 + w*32 + 16 + colid) * 8];
        #pragma unroll
        for (int mt = 0; mt < 2; mt++) {
            const bfrag a = *(const bfrag*)&sA[(kb*NPAD + mt*16 + colid) * 8];
            acc2[mt][0] = __builtin_amdgcn_mfma_f32_16x16x32_bf16(a, b0, acc2[mt][0], 0, 0, 0);
            acc2[mt][1] = __builtin_amdgcn_mfma_f32_16x16x32_bf16(a, b1, acc2[mt][1], 0, 0, 0);
        }
    }
    __syncthreads();
    {
        #pragma unroll
        for (int mt = 0; mt < 2; mt++)
            #pragma unroll
            for (int reg = 0; reg < 4; reg++) {
                const int row = mt*16 + quad*4 + reg;
                const int nidx = min(n0 + row, NN - 1);
                const float2 hr = *(const float2*)&h[(size_t)nidx*HID + f0];
                float2 o;
                o.x = acc2[mt][0][reg] + hr.x;
                o.y = acc2[mt][1][reg] + hr.y;
                *(float2*)&hres[row*130 + f0] = o;
            }
    }
    __syncthreads();
    {
        const int row = t >> 3, q = t & 7;
        float s = 0.f, s2 = 0.f;
        #pragma unroll
        for (int i = 0; i < 16; i++) {
            const float v = hres[row*130 + q*16 + i];
            s += v; s2 += v*v;
        }
        s += __shfl_xor(s, 1); s2 += __shfl_xor(s2, 1);
        s += __shfl_xor(s, 2); s2 += __shfl_xor(s2, 2);
        s += __shfl_xor(s, 4); s2 += __shfl_xor(s2, 4);
        if (q == 0) {
            const float mu = s * (1.f/HID);
            mu_s[row] = mu;
            rs_s[row] = rsqrtf(s2 * (1.f/HID) - mu*mu + 1e-5f);
        }
    }
    __syncthreads();
    for (int idx = t; idx < NPB*HID; idx += 256) {
        const int row = idx >> 7, f = idx & 127;
        const int n = n0 + row;
        if (n < NN) {
            const float v = (hres[row*130 + f] - mu_s[row]) * rs_s[row] * LG[f] + LB[f];
            h[(size_t)n*HID + f]   = v;
            hbf[(size_t)n*HID + f] = f2b(v);
        }
    }
}

// ================= MFMA output heads =================
__global__ __launch_bounds__(256) void out_mfma(
    const unsigned short* __restrict__ hbf,
    const unsigned short* __restrict__ O1p, const float* __restrict__ OB1,
    const unsigned short* __restrict__ O2p, const float* __restrict__ OB2,
    const float* __restrict__ HW, const float* __restrict__ HB,
    float* __restrict__ out)
{
    __shared__ unsigned short sA[32 * A_PAD * 8];
    __shared__ float hws[HID*3];
    const int A2O = 16 * A_PAD * 8;

    const int t = threadIdx.x, lane = t & 63, w = t >> 6;
    const int quad = lane >> 4, colid = lane & 15;
    const int n0 = blockIdx.x * 64;

    if (t < 128)      { hws[t] = HW[t]; hws[t+128] = HW[t+128]; }
    else if (t < 256) { const int i = t - 128 + 256; if (i < 384) hws[i] = HW[i]; }
    #pragma unroll
    for (int it = 0; it < 4; it++) {
        const int c = t + it * 256;
        const int e = c >> 4, kb = c & 15;
        const int nidx = min(n0 + e, NN - 1);
        *(bfrag*)&sA[(kb*A_PAD + e) * 8] = *(const bfrag*)&hbf[(size_t)nidx * HID + kb * 8];
    }
    __syncthreads();

    ffrag acc1[4][2];
    {
        const float b0v = OB1[w*32 + colid], b1v = OB1[w*32 + 16 + colid];
        #pragma unroll
        for (int mt = 0; mt < 4; mt++)
            #pragma unroll
            for (int r = 0; r < 4; r++) { acc1[mt][0][r] = b0v; acc1[mt][1][r] = b1v; }
    }
    for (int ks = 0; ks < 4; ks++) {
        const int kb = ks * 4 + quad;
        const bfrag b0 = *(const bfrag*)&O1p[((size_t)kb * 128 + w*32 + colid) * 8];
        const bfrag b1 = *(const bfrag*)&O1p[((size_t)kb * 128 + w*32 + 16 + colid) * 8];
        #pragma unroll
        for (int mt = 0; mt < 4; mt++) {
            const bfrag a = *(const bfrag*)&sA[(kb*A_PAD + mt*16 + colid) * 8];
            acc1[mt][0] = __builtin_amdgcn_mfma_f32_16x16x32_bf16(a, b0, acc1[mt][0], 0, 0, 0);
            acc1[mt][1] = __builtin_amdgcn_mfma_f32_16x16x32_bf16(a, b1, acc1[mt][1], 0, 0, 0);
        }
    }
    {
        #pragma unroll
        for (int mt = 0; mt < 4; mt++)
            #pragma unroll
            for (int nt = 0; nt < 2; nt++) {
                const int f = w*32 + nt*16 + colid;
                const int kb = f >> 3, j = f & 7;
                #pragma unroll
                for (int reg = 0; reg < 4; reg++) {
                    const float v = siluf(acc1[mt][nt][reg]);
                    const int e = mt*16 + quad*4 + reg;
                    sA[A2O + (kb*A_PAD + e) * 8 + j] = f2b(v);
                }
            }
    }
    __syncthreads();

    ffrag acco;
    {
        const float ob2v = OB2[colid];
        #pragma unroll
        for (int r = 0; r < 4; r++) acco[r] = ob2v;
    }
    for (int ks = 0; ks < 4; ks++) {
        const int kb = ks * 4 + quad;
        const bfrag a = *(const bfrag*)&sA[A2O + (kb*A_PAD + w*16 + colid) * 8];
        const bfrag b = *(const bfrag*)&O2p[((size_t)kb * 16 + colid) * 8];
        acco = __builtin_amdgcn_mfma_f32_16x16x32_bf16(a, b, acco, 0, 0, 0);
    }
    #pragma unroll
    for (int reg = 0; reg < 4; reg++) {
        const int rowg = w*16 + quad*4 + reg;
        const int n = n0 + rowg;
        if (n < NN) out[(size_t)n*OUT_DIM + colid] = acco[reg];
    }

    {
        const int rloc = t >> 2, q = t & 3;
        float s0 = 0.f, s1 = 0.f, s2 = 0.f;
        #pragma unroll
        for (int kk = 0; kk < 4; kk++) {
            const int kb = q*4 + kk;
            const bfrag v = *(const bfrag*)&sA[(kb*A_PAD + rloc) * 8];
            #pragma unroll
            for (int j = 0; j < 8; j++) {
                const float hv = b2f((unsigned short)v[j]);
                const int k = kb*8 + j;
                s0 += hv * hws[k*3+0]; s1 += hv * hws[k*3+1]; s2 += hv * hws[k*3+2];
            }
        }
        s0 += __shfl_xor(s0, 1); s1 += __shfl_xor(s1, 1); s2 += __shfl_xor(s2, 1);
        s0 += __shfl_xor(s0, 2); s1 += __shfl_xor(s1, 2); s2 += __shfl_xor(s2, 2);
        const int n = n0 + rloc;
        if (q == 0 && n < NN) {
            out[(size_t)NN*OUT_DIM + n*3 + 0] = s0 + HB[0];
            out[(size_t)NN*OUT_DIM + n*3 + 1] = s1 + HB[1];
            out[(size_t)NN*OUT_DIM + n*3 + 2] = s2 + HB[2];
        }
    }
}

extern "C" void kernel_launch(void* const* d_in, const int* in_sizes, int n_in,
                              void* d_out, int out_size, void* d_ws, size_t ws_size,
                              hipStream_t stream) {
    (void)in_sizes; (void)n_in; (void)out_size; (void)ws_size;
    const float* h_in      = (const float*)d_in[0];
    const float* x_in      = (const float*)d_in[1];
    const int*   edge_idx  = (const int*)  d_in[2];
    const float* t         = (const float*)d_in[3];
    const float* edge_attr = (const float*)d_in[4];
    const int*   batch     = (const int*)  d_in[5];
    const float* node_w = (const float*)d_in[6];
    const float* node_b = (const float*)d_in[7];
    const float* tw1    = (const float*)d_in[8];
    const float* tb1    = (const float*)d_in[9];
    const float* tw2    = (const float*)d_in[10];
    const float* tb2    = (const float*)d_in[11];
    const float* ew1    = (const float*)d_in[12];
    const float* eb1    = (const float*)d_in[13];
    const float* ew2    = (const float*)d_in[14];
    const float* eb2    = (const float*)d_in[15];
    const float* attw   = (const float*)d_in[16];
    const float* attb   = (const float*)d_in[17];
    const float* cw1    = (const float*)d_in[18];
    const float* cb1    = (const float*)d_in[19];
    const float* cw2    = (const float*)d_in[20];
    const float* nw1    = (const float*)d_in[21];
    const float* nb1    = (const float*)d_in[22];
    const float* nw2    = (const float*)d_in[23];
    const float* nb2    = (const float*)d_in[24];
    const float* lng    = (const float*)d_in[25];
    const float* lnb    = (const float*)d_in[26];
    const float* ow1    = (const float*)d_in[27];
    const float* ob1    = (const float*)d_in[28];
    const float* ow2    = (const float*)d_in[29];
    const float* ob2    = (const float*)d_in[30];
    const float* hw     = (const float*)d_in[31];
    const float* hb     = (const float*)d_in[32];

    const int* row = edge_idx;
    const int* col = edge_idx + NEDGE;

    float* ws  = (float*)d_ws;
    float* te  = ws;
    float* h   = te  + NBATCH*HID;
    float* m_i = h   + (size_t)NN*HID;
    float* x0  = m_i + (size_t)NN*HID;
    float* x1  = x0  + NN*3;
    float* Pq  = x1  + NN*3;                               // NN*128 f32
    float* Qq  = Pq  + (size_t)NN*HID;                     // NN*128 f32
    unsigned short* hbf  = (unsigned short*)(Qq + (size_t)NN*HID);
    unsigned short* eabp = hbf + (size_t)NN*HID;
    unsigned short* w1x  = eabp + (size_t)NEDGE*EDGE_DIM;  // NL*4*128*8
    unsigned short* w1rp = w1x  + (size_t)NL*4*128*8;      // NL*16*128*8
    unsigned short* w1cp = w1rp + (size_t)NL*16*128*8;     // NL*16*128*8
    unsigned short* w2p  = w1cp + (size_t)NL*16*128*8;     // NL*16*128*8
    unsigned short* c1p  = w2p  + (size_t)NL*16*128*8;     // NL*16*128*8
    unsigned short* n1p  = c1p  + (size_t)NL*16*128*8;     // NL*32*128*8
    unsigned short* n2p  = n1p  + (size_t)NL*32*128*8;     // NL*16*128*8
    unsigned short* o1p  = n2p  + (size_t)NL*16*128*8;     // 16*128*8
    unsigned short* o2p  = o1p  + (size_t)16*128*8;        // 16*16*8
    int* deg       = (int*)(o2p + (size_t)16*16*8);
    int* row_start = deg + NN;
    int* cursor    = row_start + NN + 1;
    int* rowp      = cursor + NN;
    int* colp      = rowp + NEDGE;
    int* eorder    = colp + NEDGE;

    // ---- edge sort (counting sort by row) ----
    hipMemsetAsync(deg, 0, NN*sizeof(int), stream);
    hipMemsetAsync(cursor, 0, NN*sizeof(int), stream);
    hist_kernel<<<(NEDGE+255)/256, 256, 0, stream>>>(row, deg);
    scan_kernel<<<1, 1024, 0, stream>>>(deg, row_start);
    scatter_kernel<<<(NEDGE+255)/256, 256, 0, stream>>>(row, col, row_start, cursor, rowp, colp, eorder);
    ea_pack<<<(NEDGE+255)/256, 256, 0, stream>>>(edge_attr, eorder, eabp);

    // ---- weight packs + embeddings ----
    prep_w<<<(NL*68*128 + 255)/256, 256, 0, stream>>>(ew1, ew2, cw1, w1x, w1rp, w1cp, w2p, c1p);
    prep_w2<<<(NL*32*128 + NL*16*128 + 16*128 + 16*16 + 255)/256, 256, 0, stream>>>(
        nw1, nw2, ow1, ow2, n1p, n2p, o1p, o2p);
    te_kernel<<<NBATCH, HID, 0, stream>>>(t, tw1, tb1, tw2, tb2, te);
    embed_kernel<<<NN/2, 256, 0, stream>>>(h_in, x_in, batch, node_w, node_b, te, h, hbf, x0, m_i);

    const int NBLK = (NN + NPB - 1) / NPB;   // 782
    const int OBLK = (NN + 63) / 64;         // 391
    float* xc = x0; float* xn = x1;
    for (int i = 0; i < NL; i++) {
        pq_kernel<<<OBLK, 256, 0, stream>>>(
            hbf, w1rp + (size_t)i*16*128*8, w1cp + (size_t)i*16*128*8, Pq, Qq);
        hipMemcpyAsync(xn, xc, (size_t)NN*3*sizeof(float), hipMemcpyDeviceToDevice, stream);
        edge_mfma<<<NEDGE/EPB, 256, 0, stream>>>(
            Pq, Qq, xc, xn, m_i, rowp, colp, eabp,
            w1x + (size_t)i*4*128*8, eb1 + (size_t)i*HID,
            w2p + (size_t)i*16*128*8, eb2 + (size_t)i*HID,
            c1p + (size_t)i*16*128*8, cb1 + (size_t)i*HID,
            attw + (size_t)i*HID, attb + i,
            cw2 + (size_t)i*HID);
        node_mfma<<<NBLK, 256, 0, stream>>>(
            h, hbf, m_i,
            n1p + (size_t)i*32*128*8, nb1 + (size_t)i*HID,
            n2p + (size_t)i*16*128*8, nb2 + (size_t)i*HID,
            lng + (size_t)i*HID,      lnb + (size_t)i*HID);
        float* tmp = xc; xc = xn; xn = tmp;
    }

    out_mfma<<<OBLK, 256, 0, stream>>>(hbf, o1p, ob1, o2p, ob2, hw, hb, (float*)d_out);
}

// Round 11
// 1020.220 us; speedup vs baseline: 1.0601x; 1.0601x over previous
//
#include <hip/hip_runtime.h>
#include <hip/hip_bf16.h>
#include <cmath>

#define NN      25000
#define NEDGE   400000
#define NBATCH  64
#define IN_DIM  16
#define HID     128
#define OUT_DIM 16
#define EDGE_DIM 16
#define TDIM    64
#define NL      4
#define EIN     273
#define EPB     64            // edges per block (MFMA edge kernel)
#define W2KB    16            // k-blocks for 128-K GEMMs
#define A_PAD   65            // e-dimension pad for LDS A tiles
#define A3OFF   (16*A_PAD*8)  // A3 region offset (elements) inside sA
#define NPB     32            // nodes per block (node kernel)
#define NPAD    33            // e-pad for node kernel

typedef short bfrag __attribute__((ext_vector_type(8)));
typedef float ffrag __attribute__((ext_vector_type(4)));

// fast silu/sigmoid: v_exp + v_rcp (approx) — saves the precise-division sequence
__device__ __forceinline__ float siluf(float v) { return v * __builtin_amdgcn_rcpf(1.f + __expf(-v)); }
__device__ __forceinline__ float sigm(float v)  { return __builtin_amdgcn_rcpf(1.f + __expf(-v)); }
__device__ __forceinline__ unsigned short f2b(float f) {
    unsigned u = __float_as_uint(f);
    u = (u + 0x7FFFu + ((u >> 16) & 1u)) >> 16;
    return (unsigned short)u;
}
__device__ __forceinline__ float b2f(unsigned short b) {
    return __uint_as_float(((unsigned)b) << 16);
}
// interleaved column map: slot n' holds feature ileave(n') so that thread
// (w,colid) owns adjacent features f0=w*32+2*colid (nt=0), f0+1 (nt=1)
__device__ __forceinline__ int ileave(int n) {
    return (n & 0x60) | ((n & 15) << 1) | ((n >> 4) & 1);
}

// ================= sort prep =================
__global__ __launch_bounds__(256) void hist_kernel(const int* __restrict__ row, int* __restrict__ deg) {
    const int tid = blockIdx.x * 256 + threadIdx.x;
    if (tid < NEDGE) atomicAdd(&deg[row[tid]], 1);
}

__global__ __launch_bounds__(1024) void scan_kernel(const int* __restrict__ deg, int* __restrict__ row_start) {
    __shared__ int part[1024];
    const int tid = threadIdx.x;
    const int base = tid * 25;
    int sum = 0;
    for (int i = 0; i < 25; i++) { const int idx = base + i; if (idx < NN) sum += deg[idx]; }
    part[tid] = sum;
    __syncthreads();
    for (int off = 1; off < 1024; off <<= 1) {
        int v = (tid >= off) ? part[tid - off] : 0;
        __syncthreads();
        part[tid] += v;
        __syncthreads();
    }
    int run = part[tid] - sum;
    for (int i = 0; i < 25; i++) {
        const int idx = base + i;
        if (idx < NN) { row_start[idx] = run; run += deg[idx]; }
    }
    if (tid == 1023) row_start[NN] = part[1023];
}

__global__ __launch_bounds__(256) void scatter_kernel(
    const int* __restrict__ row, const int* __restrict__ col,
    const int* __restrict__ row_start, int* __restrict__ cursor,
    int* __restrict__ rowp, int* __restrict__ colp, int* __restrict__ eorder)
{
    const int tid = blockIdx.x * 256 + threadIdx.x;
    if (tid >= NEDGE) return;
    const int r = row[tid];
    const int pos = row_start[r] + atomicAdd(&cursor[r], 1);
    rowp[pos] = r; colp[pos] = col[tid]; eorder[pos] = tid;
}

__global__ __launch_bounds__(256) void ea_pack(
    const float* __restrict__ ea, const int* __restrict__ eorder, unsigned short* __restrict__ eabp)
{
    const int tid = blockIdx.x * 256 + threadIdx.x;
    if (tid >= NEDGE) return;
    const int e = eorder[tid];
    const float4* src = (const float4*)&ea[(size_t)e * 16];
    bfrag o0, o1;
    #pragma unroll
    for (int q = 0; q < 2; q++) {
        const float4 a = src[q];
        o0[q*4+0] = (short)f2b(a.x); o0[q*4+1] = (short)f2b(a.y);
        o0[q*4+2] = (short)f2b(a.z); o0[q*4+3] = (short)f2b(a.w);
    }
    #pragma unroll
    for (int q = 0; q < 2; q++) {
        const float4 a = src[2+q];
        o1[q*4+0] = (short)f2b(a.x); o1[q*4+1] = (short)f2b(a.y);
        o1[q*4+2] = (short)f2b(a.z); o1[q*4+3] = (short)f2b(a.w);
    }
    *(bfrag*)&eabp[(size_t)tid * 16]     = o0;
    *(bfrag*)&eabp[(size_t)tid * 16 + 8] = o1;
}

// ================= prep: edge weights =================
__global__ __launch_bounds__(256) void prep_w(
    const float* __restrict__ ew1, const float* __restrict__ ew2, const float* __restrict__ cw1,
    unsigned short* __restrict__ w1x, unsigned short* __restrict__ w1rp,
    unsigned short* __restrict__ w1cp, unsigned short* __restrict__ w2p,
    unsigned short* __restrict__ c1p)
{
    const int PER_L = 68 * 128;  // 4 + 16 + 16 + 16 + 16 kblocks
    int tid = blockIdx.x * 256 + threadIdx.x;
    if (tid >= NL * PER_L) return;
    const int l = tid / PER_L, rem = tid % PER_L;
    const int kb = rem >> 7, n = rem & 127;
    unsigned short o[8];
    const float* W1 = ew1 + (size_t)l * EIN * HID;
    if (kb < 4) {
        const int nc = ileave(n);
        #pragma unroll
        for (int j = 0; j < 8; j++) {
            const int kk = kb * 8 + j;
            const int ok = (kk < 16) ? (257 + kk) : (kk == 16 ? 256 : -1);
            o[j] = (ok >= 0) ? f2b(W1[(size_t)ok * HID + nc]) : (unsigned short)0;
        }
        #pragma unroll
        for (int j = 0; j < 8; j++) w1x[(((size_t)l * 4 + kb) * 128 + n) * 8 + j] = o[j];
    } else if (kb < 20) {
        const int kb2 = kb - 4;
        const int nc = ileave(n);
        #pragma unroll
        for (int j = 0; j < 8; j++) o[j] = f2b(W1[(size_t)(kb2 * 8 + j) * HID + nc]);
        #pragma unroll
        for (int j = 0; j < 8; j++) w1rp[(((size_t)l * 16 + kb2) * 128 + n) * 8 + j] = o[j];
    } else if (kb < 36) {
        const int kb2 = kb - 20;
        const int nc = ileave(n);
        #pragma unroll
        for (int j = 0; j < 8; j++) o[j] = f2b(W1[(size_t)(128 + kb2 * 8 + j) * HID + nc]);
        #pragma unroll
        for (int j = 0; j < 8; j++) w1cp[(((size_t)l * 16 + kb2) * 128 + n) * 8 + j] = o[j];
    } else if (kb < 52) {
        const int kb2 = kb - 36;
        const float* W = ew2 + (size_t)l * HID * HID;
        const int nc = ileave(n);
        #pragma unroll
        for (int j = 0; j < 8; j++) o[j] = f2b(W[(size_t)(kb2 * 8 + j) * HID + nc]);
        #pragma unroll
        for (int j = 0; j < 8; j++) w2p[(((size_t)l * W2KB + kb2) * 128 + n) * 8 + j] = o[j];
    } else {
        const int kb2 = kb - 52;
        const float* W = cw1 + (size_t)l * HID * HID;
        #pragma unroll
        for (int j = 0; j < 8; j++) o[j] = f2b(W[(size_t)(kb2 * 8 + j) * HID + n]);
        #pragma unroll
        for (int j = 0; j < 8; j++) c1p[(((size_t)l * W2KB + kb2) * 128 + n) * 8 + j] = o[j];
    }
}

// ================= prep: node/out weights =================
__global__ __launch_bounds__(256) void prep_w2(
    const float* __restrict__ nw1, const float* __restrict__ nw2,
    const float* __restrict__ ow1, const float* __restrict__ ow2,
    unsigned short* __restrict__ n1p, unsigned short* __restrict__ n2p,
    unsigned short* __restrict__ o1p, unsigned short* __restrict__ o2p)
{
    const int C1 = NL * 32 * 128;
    const int C2 = C1 + NL * 16 * 128;
    const int C3 = C2 + 16 * 128;
    const int C4 = C3 + 16 * 16;
    int tid = blockIdx.x * 256 + threadIdx.x;
    if (tid >= C4) return;
    if (tid < C1) {
        const int l = tid / (32*128), rem = tid % (32*128);
        const int kb = rem >> 7, n = rem & 127;
        const int nc = ileave(n);
        #pragma unroll
        for (int j = 0; j < 8; j++)
            n1p[(size_t)tid*8 + j] = f2b(nw1[((size_t)l*256 + kb*8 + j)*128 + nc]);
    } else if (tid < C2) {
        const int t2 = tid - C1;
        const int l = t2 / (16*128), rem = t2 % (16*128);
        const int kb = rem >> 7, n = rem & 127;
        const int nc = ileave(n);
        #pragma unroll
        for (int j = 0; j < 8; j++)
            n2p[(size_t)t2*8 + j] = f2b(nw2[((size_t)l*128 + kb*8 + j)*128 + nc]);
    } else if (tid < C3) {
        const int t2 = tid - C2;
        const int kb = t2 >> 7, n = t2 & 127;
        #pragma unroll
        for (int j = 0; j < 8; j++)
            o1p[(size_t)t2*8 + j] = f2b(ow1[(size_t)(kb*8 + j)*128 + n]);
    } else {
        const int t2 = tid - C3;
        const int kb = t2 >> 4, n = t2 & 15;
        #pragma unroll
        for (int j = 0; j < 8; j++)
            o2p[(size_t)t2*8 + j] = f2b(ow2[(size_t)(kb*8 + j)*16 + n]);
    }
}

// ================= time embedding =================
__global__ __launch_bounds__(HID) void te_kernel(
    const float* __restrict__ t, const float* __restrict__ tw1, const float* __restrict__ tb1,
    const float* __restrict__ tw2, const float* __restrict__ tb2, float* __restrict__ te_out)
{
    __shared__ float s0[TDIM];
    __shared__ float s1[HID];
    const int b = blockIdx.x, j = threadIdx.x;
    const float tv = t[b];
    if (j < TDIM) {
        const int k = j & 31;
        const float freq = expf((float)k * (-logf(10000.f) / 31.f));
        const float a = tv * freq;
        s0[j] = (j < 32) ? sinf(a) : cosf(a);
    }
    __syncthreads();
    float acc = tb1[j];
    for (int k = 0; k < TDIM; k++) acc += s0[k] * tw1[k*HID + j];
    s1[j] = siluf(acc);
    __syncthreads();
    float acc2 = tb2[j];
    for (int k = 0; k < HID; k++) acc2 += s1[k] * tw2[k*HID + j];
    te_out[b*HID + j] = acc2;
}

// ================= node embedding: 2 nodes/block; zeroes m_i for layer 0 =================
__global__ __launch_bounds__(256) void embed_kernel(
    const float* __restrict__ h_in, const float* __restrict__ x_in,
    const int* __restrict__ batch,
    const float* __restrict__ node_w, const float* __restrict__ node_b,
    const float* __restrict__ te, float* __restrict__ h, unsigned short* __restrict__ hbf,
    float* __restrict__ x0, float* __restrict__ m_i)
{
    __shared__ float hs[2][IN_DIM];
    const int local = threadIdx.x >> 7;
    const int j = threadIdx.x & 127;
    const int n = blockIdx.x * 2 + local;
    if (j < IN_DIM) hs[local][j] = h_in[n*IN_DIM + j];
    if (j >= 64 && j < 67) x0[n*3 + (j - 64)] = x_in[n*3 + (j - 64)];
    __syncthreads();
    float acc = node_b[j];
    #pragma unroll
    for (int k = 0; k < IN_DIM; k++) acc += hs[local][k] * node_w[k*HID + j];
    acc += te[batch[n]*HID + j];
    h[(size_t)n*HID + j]   = acc;
    hbf[(size_t)n*HID + j] = f2b(acc);
    m_i[(size_t)n*HID + j] = 0.f;
}

// ================= per-layer precompute: P = h@W1row, Q = h@W1col (bf16 out) =================
__global__ __launch_bounds__(256) void pq_kernel(
    const unsigned short* __restrict__ hbf,
    const unsigned short* __restrict__ Wr, const unsigned short* __restrict__ Wc,
    unsigned short* __restrict__ P, unsigned short* __restrict__ Q)
{
    __shared__ unsigned short sA[16 * A_PAD * 8];
    const int t = threadIdx.x, lane = t & 63, w = t >> 6;
    const int quad = lane >> 4, colid = lane & 15;
    const int n0 = blockIdx.x * 64;

    #pragma unroll
    for (int it = 0; it < 4; it++) {
        const int c = t + it * 256;
        const int e = c >> 4, kb = c & 15;
        const int nidx = min(n0 + e, NN - 1);
        *(bfrag*)&sA[(kb*A_PAD + e) * 8] = *(const bfrag*)&hbf[(size_t)nidx * HID + kb * 8];
    }
    __syncthreads();

    ffrag aP[4][2] = {}, aQ[4][2] = {};
    for (int ks = 0; ks < 4; ks++) {
        const int kb = ks * 4 + quad;
        const bfrag p0 = *(const bfrag*)&Wr[((size_t)kb * 128 + w*32 + colid) * 8];
        const bfrag p1 = *(const bfrag*)&Wr[((size_t)kb * 128 + w*32 + 16 + colid) * 8];
        const bfrag q0 = *(const bfrag*)&Wc[((size_t)kb * 128 + w*32 + colid) * 8];
        const bfrag q1 = *(const bfrag*)&Wc[((size_t)kb * 128 + w*32 + 16 + colid) * 8];
        #pragma unroll
        for (int mt = 0; mt < 4; mt++) {
            const bfrag a = *(const bfrag*)&sA[(kb*A_PAD + mt*16 + colid) * 8];
            aP[mt][0] = __builtin_amdgcn_mfma_f32_16x16x32_bf16(a, p0, aP[mt][0], 0, 0, 0);
            aP[mt][1] = __builtin_amdgcn_mfma_f32_16x16x32_bf16(a, p1, aP[mt][1], 0, 0, 0);
            aQ[mt][0] = __builtin_amdgcn_mfma_f32_16x16x32_bf16(a, q0, aQ[mt][0], 0, 0, 0);
            aQ[mt][1] = __builtin_amdgcn_mfma_f32_16x16x32_bf16(a, q1, aQ[mt][1], 0, 0, 0);
        }
    }
    const int f0 = w*32 + 2*colid;
    #pragma unroll
    for (int mt = 0; mt < 4; mt++)
        #pragma unroll
        for (int reg = 0; reg < 4; reg++) {
            const int n = n0 + mt*16 + quad*4 + reg;
            if (n < NN) {
                *(__hip_bfloat162*)&P[(size_t)n*HID + f0] =
                    __float22bfloat162_rn(make_float2(aP[mt][0][reg], aP[mt][1][reg]));
                *(__hip_bfloat162*)&Q[(size_t)n*HID + f0] =
                    __float22bfloat162_rn(make_float2(aQ[mt][0][reg], aQ[mt][1][reg]));
            }
        }
}

// ================= fused MFMA edge kernel (row-sorted edges) =================
__global__ __launch_bounds__(256) void edge_mfma(
    const unsigned short* __restrict__ P, const unsigned short* __restrict__ Q,
    const float* __restrict__ x,
    float* __restrict__ x_new, float* __restrict__ m_i,
    const int* __restrict__ rowp, const int* __restrict__ colp,
    const unsigned short* __restrict__ eabp,
    const unsigned short* __restrict__ W1X, const float* __restrict__ B1,
    const unsigned short* __restrict__ W2p, const float* __restrict__ B2,
    const unsigned short* __restrict__ C1p, const float* __restrict__ CB1,
    const float* __restrict__ AW, const float* __restrict__ ABv,
    const float* __restrict__ CW2)
{
    __shared__ unsigned short sA[32 * A_PAD * 8];  // A2 = kb0..15; A3 at A3OFF (Aea aliases A3 start)
    __shared__ int rc[EPB][2];
    __shared__ float AWs[HID];
    float* scr  = (float*)sA;       // aliases dead A2 region during epilogues
    float* attS = scr;              // [64]
    float* pscr = scr;              // [64 k][66] coord partials; alive only after final sync

    const int t = threadIdx.x;
    const int e0 = blockIdx.x * EPB;
    const int lane = t & 63, w = t >> 6;
    const int quad = lane >> 4, colid = lane & 15;
    const int f0 = w*32 + 2*colid;

    // ---- stage: rc, coord-diff, ea + radial into Aea (A3 region), AW ----
    float cd0 = 0.f, cd1 = 0.f, cd2 = 0.f;
    if (t < EPB) {
        const int r = rowp[e0 + t], c = colp[e0 + t];
        rc[t][0] = r; rc[t][1] = c;
        const float dx = x[r*3+0] - x[c*3+0];
        const float dy = x[r*3+1] - x[c*3+1];
        const float dz = x[r*3+2] - x[c*3+2];
        const float rad = dx*dx + dy*dy + dz*dz;
        const float inv = 1.f / sqrtf(rad + 1e-8f);
        cd0 = dx*inv; cd1 = dy*inv; cd2 = dz*inv;
        unsigned short* p2 = &sA[A3OFF + (2*A_PAD + t) * 8];   // Aea kb2: [radial, 0..]
        p2[0] = f2b(rad);
        #pragma unroll
        for (int j = 1; j < 8; j++) p2[j] = 0;
        unsigned short* p3 = &sA[A3OFF + (3*A_PAD + t) * 8];   // Aea kb3: zeros
        #pragma unroll
        for (int j = 0; j < 8; j++) p3[j] = 0;
    }
    if (t >= 128 && t < 256) AWs[t - 128] = AW[t - 128];
    if (t < 128) {
        const int e = t >> 1, hh = t & 1;
        *(bfrag*)&sA[A3OFF + (hh*A_PAD + e) * 8] = *(const bfrag*)&eabp[(size_t)(e0 + e) * 16 + hh * 8];
    }
    __syncthreads();

    // ---- PREFETCH: issue all 32 P/Q gathers now (bf16 u32, covers f0,f0+1);
    //      ~500 cyc of MFMA + LDS work below hides the L2/L3 latency ----
    unsigned pv[16], qv[16];
    #pragma unroll
    for (int i = 0; i < 16; i++) {
        const int e = (i >> 2)*16 + quad*4 + (i & 3);   // [mt][reg] order
        pv[i] = *(const unsigned*)&P[(size_t)rc[e][0]*HID + f0];
        qv[i] = *(const unsigned*)&Q[(size_t)rc[e][1]*HID + f0];
    }

    // ---- GEMM_ea: [64 x 32] @ [32 x 128] (K=32: ea|radial), bias B1 preloaded ----
    ffrag accea[4][2];
    {
        const float b0v = B1[f0], b1v = B1[f0+1];
        #pragma unroll
        for (int mt = 0; mt < 4; mt++)
            #pragma unroll
            for (int r = 0; r < 4; r++) { accea[mt][0][r] = b0v; accea[mt][1][r] = b1v; }
    }
    {
        const bfrag eb0 = *(const bfrag*)&W1X[((size_t)quad * 128 + w*32 + colid) * 8];
        const bfrag eb1 = *(const bfrag*)&W1X[((size_t)quad * 128 + w*32 + 16 + colid) * 8];
        #pragma unroll
        for (int mt = 0; mt < 4; mt++) {
            const bfrag a = *(const bfrag*)&sA[A3OFF + (quad*A_PAD + mt*16 + colid) * 8];
            accea[mt][0] = __builtin_amdgcn_mfma_f32_16x16x32_bf16(a, eb0, accea[mt][0], 0, 0, 0);
            accea[mt][1] = __builtin_amdgcn_mfma_f32_16x16x32_bf16(a, eb1, accea[mt][1], 0, 0, 0);
        }
    }

    // ---- epilogue 1: m1 = silu(P[row] + Q[col] + ea_part), packed bf16x2 -> A2 ----
    {
        const int kb = f0 >> 3, j = f0 & 7;
        #pragma unroll
        for (int mt = 0; mt < 4; mt++)
            #pragma unroll
            for (int reg = 0; reg < 4; reg++) {
                const int i = mt*4 + reg;
                const int e = mt*16 + quad*4 + reg;
                const float v0 = siluf(__uint_as_float(pv[i] << 16)
                                     + __uint_as_float(qv[i] << 16) + accea[mt][0][reg]);
                const float v1 = siluf(__uint_as_float(pv[i] & 0xFFFF0000u)
                                     + __uint_as_float(qv[i] & 0xFFFF0000u) + accea[mt][1][reg]);
                *(__hip_bfloat162*)&sA[(kb*A_PAD + e) * 8 + j] =
                    __float22bfloat162_rn(make_float2(v0, v1));   // A2
            }
    }
    __syncthreads();

    // ---- GEMM2: [64 x 128] @ [128 x 128] (interleaved columns) ----
    ffrag acc2[4][2] = {};
    for (int ks = 0; ks < 4; ks++) {
        const int kb = ks * 4 + quad;
        const bfrag b0 = *(const bfrag*)&W2p[((size_t)kb * 128 + w*32 + colid) * 8];
        const bfrag b1 = *(const bfrag*)&W2p[((size_t)kb * 128 + w*32 + 16 + colid) * 8];
        #pragma unroll
        for (int mt = 0; mt < 4; mt++) {
            const bfrag a = *(const bfrag*)&sA[(kb*A_PAD + mt*16 + colid) * 8];
            acc2[mt][0] = __builtin_amdgcn_mfma_f32_16x16x32_bf16(a, b0, acc2[mt][0], 0, 0, 0);
            acc2[mt][1] = __builtin_amdgcn_mfma_f32_16x16x32_bf16(a, b1, acc2[mt][1], 0, 0, 0);
        }
    }
    // ---- epilogue 2: silu -> packed bf16x2 UNSCALED m2 into A3 ----
    {
        const int kb = f0 >> 3, j = f0 & 7;
        const float b0v = B2[f0], b1v = B2[f0+1];
        #pragma unroll
        for (int mt = 0; mt < 4; mt++)
            #pragma unroll
            for (int reg = 0; reg < 4; reg++) {
                const float v0 = siluf(acc2[mt][0][reg] + b0v);
                const float v1 = siluf(acc2[mt][1][reg] + b1v);
                const int e = mt*16 + quad*4 + reg;
                *(__hip_bfloat162*)&sA[A3OFF + (kb*A_PAD + e) * 8 + j] =
                    __float22bfloat162_rn(make_float2(v0, v1));
            }
    }
    __syncthreads();   // A3 visible; A2 dead (scr region safe)

    // ---- attention: att[e] = sigmoid(m2[e] . AW + ab) ----
    {
        const int e = t >> 2, q = t & 3;
        float s = 0.f;
        #pragma unroll
        for (int kk = 0; kk < 4; kk++) {
            const int kb = q*4 + kk;
            const bfrag v = *(const bfrag*)&sA[A3OFF + (kb*A_PAD + e) * 8];
            #pragma unroll
            for (int j = 0; j < 8; j++) s += b2f((unsigned short)v[j]) * AWs[kb*8 + j];
        }
        s += __shfl_xor(s, 1);
        s += __shfl_xor(s, 2);
        if (q == 0) attS[e] = sigm(s + ABv[0]);
    }
    __syncthreads();

    // ---- GEMM3 on UNSCALED m2: [64 x 128] @ CW1 [128 x 128] (canonical cols) ----
    ffrag acc3[4][2] = {};
    for (int ks = 0; ks < 4; ks++) {
        const int kb = ks * 4 + quad;
        const bfrag b0 = *(const bfrag*)&C1p[((size_t)kb * 128 + w*32 + colid) * 8];
        const bfrag b1 = *(const bfrag*)&C1p[((size_t)kb * 128 + w*32 + 16 + colid) * 8];
        #pragma unroll
        for (int mt = 0; mt < 4; mt++) {
            const bfrag a = *(const bfrag*)&sA[A3OFF + (kb*A_PAD + mt*16 + colid) * 8];
            acc3[mt][0] = __builtin_amdgcn_mfma_f32_16x16x32_bf16(a, b0, acc3[mt][0], 0, 0, 0);
            acc3[mt][1] = __builtin_amdgcn_mfma_f32_16x16x32_bf16(a, b1, acc3[mt][1], 0, 0, 0);
        }
    }

    // ---- m_i segmented reduction: READ-ONLY, scaled on the fly ----
    {
        const int fkb0 = lane >> 3,     fj = lane & 7;     // f = lane
        const int fkb1 = 8 + (lane >> 3);                   // f = lane + 64
        float a0 = 0.f, a1 = 0.f;
        for (int i = 0; i < 16; i++) {
            const int e = (w << 4) + i;
            const float av = attS[e];
            const int r = rc[e][0];
            a0 += b2f(sA[A3OFF + (fkb0*A_PAD + e) * 8 + fj]) * av;
            a1 += b2f(sA[A3OFF + (fkb1*A_PAD + e) * 8 + fj]) * av;
            const bool flush = (i == 15) || (rc[e+1][0] != r);
            if (flush) {
                atomicAdd(&m_i[(size_t)r * HID + lane],      a0);
                atomicAdd(&m_i[(size_t)r * HID + lane + 64], a1);
                a0 = 0.f; a1 = 0.f;
            }
        }
    }

    // ---- GEMM3 epilogue: att applied here (row-scaling commutes), coord partials ----
    float p[4][4];
    {
        const float cb0v = CB1[w*32 + colid], cb1v = CB1[w*32 + 16 + colid];
        const float cwv0 = CW2[w*32 + colid], cwv1 = CW2[w*32 + 16 + colid];
        #pragma unroll
        for (int mt = 0; mt < 4; mt++) {
            const float4 a4 = *(const float4*)&attS[mt*16 + quad*4];
            const float att_r[4] = {a4.x, a4.y, a4.z, a4.w};
            #pragma unroll
            for (int reg = 0; reg < 4; reg++)
                p[mt][reg] = siluf(att_r[reg] * acc3[mt][0][reg] + cb0v) * cwv0
                           + siluf(att_r[reg] * acc3[mt][1][reg] + cb1v) * cwv1;
        }
    }
    __syncthreads();   // all A3/attS reads done; pscr may now overwrite A2/A3
    // scatter: pscr[k][e] stride 66 (write banks ~2-way, read banks conflict-free)
    {
        const int k = w*16 + colid;
        #pragma unroll
        for (int mt = 0; mt < 4; mt++)
            #pragma unroll
            for (int rr = 0; rr < 2; rr++) {
                const int e = mt*16 + quad*4 + rr*2;
                *(float2*)&pscr[k*66 + e] = make_float2(p[mt][rr*2], p[mt][rr*2+1]);
            }
    }
    __syncthreads();
    if (t < EPB) {
        float s = 0.f;
        #pragma unroll
        for (int k2 = 0; k2 < 64; k2++) s += pscr[k2*66 + t];
        const int r = rc[t][0];
        atomicAdd(&x_new[r*3+0], cd0 * s);
        atomicAdd(&x_new[r*3+1], cd1 * s);
        atomicAdd(&x_new[r*3+2], cd2 * s);
    }
}

// ================= MFMA node MLP + residual + layernorm (32 nodes/block); zeroes m_i =================
__global__ __launch_bounds__(256) void node_mfma(
    float* __restrict__ h, unsigned short* __restrict__ hbf, float* __restrict__ m_i,
    const unsigned short* __restrict__ N1p, const float* __restrict__ NB1,
    const unsigned short* __restrict__ N2p, const float* __restrict__ NB2,
    const float* __restrict__ LG, const float* __restrict__ LB)
{
    __shared__ unsigned short sA[32 * NPAD * 8];
    __shared__ float mu_s[NPB], rs_s[NPB];
    float* hres = (float*)sA;                       // [32][130] fp32

    const int t = threadIdx.x, lane = t & 63, w = t >> 6;
    const int quad = lane >> 4, colid = lane & 15;
    const int n0 = blockIdx.x * NPB;

    #pragma unroll
    for (int it = 0; it < 2; it++) {
        const int c = t + it * 256;
        const int e = c >> 4, kb = c & 15;
        const int nidx = min(n0 + e, NN - 1);
        *(bfrag*)&sA[(kb*NPAD + e) * 8] = *(const bfrag*)&hbf[(size_t)nidx * HID + kb * 8];
    }
    #pragma unroll
    for (int it = 0; it < 2; it++) {
        const int c = t + it * 256;
        const int e = c >> 4, kb = c & 15;
        const int nidx = min(n0 + e, NN - 1);
        const float4 v0 = *(const float4*)&m_i[(size_t)nidx * HID + kb * 8];
        const float4 v1 = *(const float4*)&m_i[(size_t)nidx * HID + kb * 8 + 4];
        bfrag bv;
        bv[0]=(short)f2b(v0.x); bv[1]=(short)f2b(v0.y); bv[2]=(short)f2b(v0.z); bv[3]=(short)f2b(v0.w);
        bv[4]=(short)f2b(v1.x); bv[5]=(short)f2b(v1.y); bv[6]=(short)f2b(v1.z); bv[7]=(short)f2b(v1.w);
        *(bfrag*)&sA[((16 + kb)*NPAD + e) * 8] = bv;
        if (n0 + e < NN) {
            const float4 z4 = {0.f, 0.f, 0.f, 0.f};
            *(float4*)&m_i[(size_t)nidx * HID + kb * 8]     = z4;
            *(float4*)&m_i[(size_t)nidx * HID + kb * 8 + 4] = z4;
        }
    }
    __syncthreads();

    const int f0 = w*32 + 2*colid;
    ffrag acc1[2][2];
    {
        const float b0v = NB1[f0], b1v = NB1[f0+1];
        #pragma unroll
        for (int mt = 0; mt < 2; mt++)
            #pragma unroll
            for (int r = 0; r < 4; r++) { acc1[mt][0][r] = b0v; acc1[mt][1][r] = b1v; }
    }
    for (int ks = 0; ks < 8; ks++) {
        const int kb = ks * 4 + quad;
        const bfrag b0 = *(const bfrag*)&N1p[((size_t)kb * 128 + w*32 + colid) * 8];
        const bfrag b1 = *(const bfrag*)&N1p[((size_t)kb * 128 + w*32 + 16 + colid) * 8];
        #pragma unroll
        for (int mt = 0; mt < 2; mt++) {
            const bfrag a = *(const bfrag*)&sA[(kb*NPAD + mt*16 + colid) * 8];
            acc1[mt][0] = __builtin_amdgcn_mfma_f32_16x16x32_bf16(a, b0, acc1[mt][0], 0, 0, 0);
            acc1[mt][1] = __builtin_amdgcn_mfma_f32_16x16x32_bf16(a, b1, acc1[mt][1], 0, 0, 0);
        }
    }
    __syncthreads();
    {
        const int kb = f0 >> 3, j = f0 & 7;
        #pragma unroll
        for (int mt = 0; mt < 2; mt++)
            #pragma unroll
            for (int reg = 0; reg < 4; reg++) {
                const float v0 = siluf(acc1[mt][0][reg]);
                const float v1 = siluf(acc1[mt][1][reg]);
                const int e = mt*16 + quad*4 + reg;
                *(__hip_bfloat162*)&sA[(kb*NPAD + e) * 8 + j] =
                    __float22bfloat162_rn(make_float2(v0, v1));
            }
    }
    __syncthreads();

    ffrag acc2[2][2];
    {
        const float b0v = NB2[f0], b1v = NB2[f0+1];
        #pragma unroll
        for (int mt = 0; mt < 2; mt++)
            #pragma unroll
            for (int r = 0; r < 4; r++) { acc2[mt][0][r] = b0v; acc2[mt][1][r] = b1v; }
    }
    for (int ks = 0; ks < 4; ks++) {
        const int kb = ks * 4 + quad;
        const bfrag b0 = *(const bfrag*)&N2p[((size_t)kb * 128 + w*32 + colid) * 8];
        const bfrag b1 = *(const bfrag*)&N2p[((size_t)kb * 128 + w*32 + 16 + colid) * 8];
        #pragma unroll
        for (int mt = 0; mt < 2; mt++) {
            const bfrag a = *(const bfrag*)&sA[(kb*NPAD + mt*16 + colid) * 8];
            acc2[mt][0] = __builtin_amdgcn_mfma_f32_16x16x32_bf16(a, b0, acc2[mt][0], 0, 0, 0);
            acc2[mt][1] = __builtin_amdgcn_mfma_f32_16x16x32_bf16(a, b1, acc2[mt][1], 0, 0, 0);
        }
    }
    __syncthreads();
    {
        #pragma unroll
        for (int mt = 0; mt < 2; mt++)
            #pragma unroll
            for (int reg = 0; reg < 4; reg++) {
                const int row = mt*16 + quad*4 + reg;
                const int nidx = min(n0 + row, NN - 1);
                const float2 hr = *(const float2*)&h[(size_t)nidx*HID + f0];
                float2 o;
                o.x = acc2[mt][0][reg] + hr.x;
                o.y = acc2[mt][1][reg] + hr.y;
                *(float2*)&hres[row*130 + f0] = o;
            }
    }
    __syncthreads();
    {
        const int row = t >> 3, q = t & 7;
        float s = 0.f, s2 = 0.f;
        #pragma unroll
        for (int i = 0; i < 16; i++) {
            const float v = hres[row*130 + q*16 + i];
            s += v; s2 += v*v;
        }
        s += __shfl_xor(s, 1); s2 += __shfl_xor(s2, 1);
        s += __shfl_xor(s, 2); s2 += __shfl_xor(s2, 2);
        s += __shfl_xor(s, 4); s2 += __shfl_xor(s2, 4);
        if (q == 0) {
            const float mu = s * (1.f/HID);
            mu_s[row] = mu;
            rs_s[row] = rsqrtf(s2 * (1.f/HID) - mu*mu + 1e-5f);
        }
    }
    __syncthreads();
    for (int idx = t; idx < NPB*HID; idx += 256) {
        const int row = idx >> 7, f = idx & 127;
        const int n = n0 + row;
        if (n < NN) {
            const float v = (hres[row*130 + f] - mu_s[row]) * rs_s[row] * LG[f] + LB[f];
            h[(size_t)n*HID + f]   = v;
            hbf[(size_t)n*HID + f] = f2b(v);
        }
    }
}

// ================= MFMA output heads =================
__global__ __launch_bounds__(256) void out_mfma(
    const unsigned short* __restrict__ hbf,
    const unsigned short* __restrict__ O1p, const float* __restrict__ OB1,
    const unsigned short* __restrict__ O2p, const float* __restrict__ OB2,
    const float* __restrict__ HW, const float* __restrict__ HB,
    float* __restrict__ out)
{
    __shared__ unsigned short sA[32 * A_PAD * 8];
    __shared__ float hws[HID*3];
    const int A2O = 16 * A_PAD * 8;

    const int t = threadIdx.x, lane = t & 63, w = t >> 6;
    const int quad = lane >> 4, colid = lane & 15;
    const int n0 = blockIdx.x * 64;

    if (t < 128)      { hws[t] = HW[t]; hws[t+128] = HW[t+128]; }
    else if (t < 256) { const int i = t - 128 + 256; if (i < 384) hws[i] = HW[i]; }
    #pragma unroll
    for (int it = 0; it < 4; it++) {
        const int c = t + it * 256;
        const int e = c >> 4, kb = c & 15;
        const int nidx = min(n0 + e, NN - 1);
        *(bfrag*)&sA[(kb*A_PAD + e) * 8] = *(const bfrag*)&hbf[(size_t)nidx * HID + kb * 8];
    }
    __syncthreads();

    ffrag acc1[4][2];
    {
        const float b0v = OB1[w*32 + colid], b1v = OB1[w*32 + 16 + colid];
        #pragma unroll
        for (int mt = 0; mt < 4; mt++)
            #pragma unroll
            for (int r = 0; r < 4; r++) { acc1[mt][0][r] = b0v; acc1[mt][1][r] = b1v; }
    }
    for (int ks = 0; ks < 4; ks++) {
        const int kb = ks * 4 + quad;
        const bfrag b0 = *(const bfrag*)&O1p[((size_t)kb * 128 + w*32 + colid) * 8];
        const bfrag b1 = *(const bfrag*)&O1p[((size_t)kb * 128 + w*32 + 16 + colid) * 8];
        #pragma unroll
        for (int mt = 0; mt < 4; mt++) {
            const bfrag a = *(const bfrag*)&sA[(kb*A_PAD + mt*16 + colid) * 8];
            acc1[mt][0] = __builtin_amdgcn_mfma_f32_16x16x32_bf16(a, b0, acc1[mt][0], 0, 0, 0);
            acc1[mt][1] = __builtin_amdgcn_mfma_f32_16x16x32_bf16(a, b1, acc1[mt][1], 0, 0, 0);
        }
    }
    {
        #pragma unroll
        for (int mt = 0; mt < 4; mt++)
            #pragma unroll
            for (int nt = 0; nt < 2; nt++) {
                const int f = w*32 + nt*16 + colid;
                const int kb = f >> 3, j = f & 7;
                #pragma unroll
                for (int reg = 0; reg < 4; reg++) {
                    const float v = siluf(acc1[mt][nt][reg]);
                    const int e = mt*16 + quad*4 + reg;
                    sA[A2O + (kb*A_PAD + e) * 8 + j] = f2b(v);
                }
            }
    }
    __syncthreads();

    ffrag acco;
    {
        const float ob2v = OB2[colid];
        #pragma unroll
        for (int r = 0; r < 4; r++) acco[r] = ob2v;
    }
    for (int ks = 0; ks < 4; ks++) {
        const int kb = ks * 4 + quad;
        const bfrag a = *(const bfrag*)&sA[A2O + (kb*A_PAD + w*16 + colid) * 8];
        const bfrag b = *(const bfrag*)&O2p[((size_t)kb * 16 + colid) * 8];
        acco = __builtin_amdgcn_mfma_f32_16x16x32_bf16(a, b, acco, 0, 0, 0);
    }
    #pragma unroll
    for (int reg = 0; reg < 4; reg++) {
        const int rowg = w*16 + quad*4 + reg;
        const int n = n0 + rowg;
        if (n < NN) out[(size_t)n*OUT_DIM + colid] = acco[reg];
    }

    {
        const int rloc = t >> 2, q = t & 3;
        float s0 = 0.f, s1 = 0.f, s2 = 0.f;
        #pragma unroll
        for (int kk = 0; kk < 4; kk++) {
            const int kb = q*4 + kk;
            const bfrag v = *(const bfrag*)&sA[(kb*A_PAD + rloc) * 8];
            #pragma unroll
            for (int j = 0; j < 8; j++) {
                const float hv = b2f((unsigned short)v[j]);
                const int k = kb*8 + j;
                s0 += hv * hws[k*3+0]; s1 += hv * hws[k*3+1]; s2 += hv * hws[k*3+2];
            }
        }
        s0 += __shfl_xor(s0, 1); s1 += __shfl_xor(s1, 1); s2 += __shfl_xor(s2, 1);
        s0 += __shfl_xor(s0, 2); s1 += __shfl_xor(s1, 2); s2 += __shfl_xor(s2, 2);
        const int n = n0 + rloc;
        if (q == 0 && n < NN) {
            out[(size_t)NN*OUT_DIM + n*3 + 0] = s0 + HB[0];
            out[(size_t)NN*OUT_DIM + n*3 + 1] = s1 + HB[1];
            out[(size_t)NN*OUT_DIM + n*3 + 2] = s2 + HB[2];
        }
    }
}

extern "C" void kernel_launch(void* const* d_in, const int* in_sizes, int n_in,
                              void* d_out, int out_size, void* d_ws, size_t ws_size,
                              hipStream_t stream) {
    (void)in_sizes; (void)n_in; (void)out_size; (void)ws_size;
    const float* h_in      = (const float*)d_in[0];
    const float* x_in      = (const float*)d_in[1];
    const int*   edge_idx  = (const int*)  d_in[2];
    const float* t         = (const float*)d_in[3];
    const float* edge_attr = (const float*)d_in[4];
    const int*   batch     = (const int*)  d_in[5];
    const float* node_w = (const float*)d_in[6];
    const float* node_b = (const float*)d_in[7];
    const float* tw1    = (const float*)d_in[8];
    const float* tb1    = (const float*)d_in[9];
    const float* tw2    = (const float*)d_in[10];
    const float* tb2    = (const float*)d_in[11];
    const float* ew1    = (const float*)d_in[12];
    const float* eb1    = (const float*)d_in[13];
    const float* ew2    = (const float*)d_in[14];
    const float* eb2    = (const float*)d_in[15];
    const float* attw   = (const float*)d_in[16];
    const float* attb   = (const float*)d_in[17];
    const float* cw1    = (const float*)d_in[18];
    const float* cb1    = (const float*)d_in[19];
    const float* cw2    = (const float*)d_in[20];
    const float* nw1    = (const float*)d_in[21];
    const float* nb1    = (const float*)d_in[22];
    const float* nw2    = (const float*)d_in[23];
    const float* nb2    = (const float*)d_in[24];
    const float* lng    = (const float*)d_in[25];
    const float* lnb    = (const float*)d_in[26];
    const float* ow1    = (const float*)d_in[27];
    const float* ob1    = (const float*)d_in[28];
    const float* ow2    = (const float*)d_in[29];
    const float* ob2    = (const float*)d_in[30];
    const float* hw     = (const float*)d_in[31];
    const float* hb     = (const float*)d_in[32];

    const int* row = edge_idx;
    const int* col = edge_idx + NEDGE;

    float* ws  = (float*)d_ws;
    float* te  = ws;
    float* h   = te  + NBATCH*HID;
    float* m_i = h   + (size_t)NN*HID;
    float* x0  = m_i + (size_t)NN*HID;
    float* x1  = x0  + NN*3;
    unsigned short* hbf  = (unsigned short*)(x1 + NN*3);
    unsigned short* eabp = hbf + (size_t)NN*HID;
    unsigned short* w1x  = eabp + (size_t)NEDGE*EDGE_DIM;  // NL*4*128*8
    unsigned short* w1rp = w1x  + (size_t)NL*4*128*8;      // NL*16*128*8
    unsigned short* w1cp = w1rp + (size_t)NL*16*128*8;     // NL*16*128*8
    unsigned short* w2p  = w1cp + (size_t)NL*16*128*8;     // NL*16*128*8
    unsigned short* c1p  = w2p  + (size_t)NL*16*128*8;     // NL*16*128*8
    unsigned short* n1p  = c1p  + (size_t)NL*16*128*8;     // NL*32*128*8
    unsigned short* n2p  = n1p  + (size_t)NL*32*128*8;     // NL*16*128*8
    unsigned short* o1p  = n2p  + (size_t)NL*16*128*8;     // 16*128*8
    unsigned short* o2p  = o1p  + (size_t)16*128*8;        // 16*16*8
    unsigned short* Pq   = o2p  + (size_t)16*16*8;         // NN*128 bf16
    unsigned short* Qq   = Pq   + (size_t)NN*HID;          // NN*128 bf16
    int* deg       = (int*)(Qq + (size_t)NN*HID);
    int* row_start = deg + NN;
    int* cursor    = row_start + NN + 1;
    int* rowp      = cursor + NN;
    int* colp      = rowp + NEDGE;
    int* eorder    = colp + NEDGE;

    // ---- edge sort (counting sort by row) ----
    hipMemsetAsync(deg, 0, NN*sizeof(int), stream);
    hipMemsetAsync(cursor, 0, NN*sizeof(int), stream);
    hist_kernel<<<(NEDGE+255)/256, 256, 0, stream>>>(row, deg);
    scan_kernel<<<1, 1024, 0, stream>>>(deg, row_start);
    scatter_kernel<<<(NEDGE+255)/256, 256, 0, stream>>>(row, col, row_start, cursor, rowp, colp, eorder);
    ea_pack<<<(NEDGE+255)/256, 256, 0, stream>>>(edge_attr, eorder, eabp);

    // ---- weight packs + embeddings ----
    prep_w<<<(NL*68*128 + 255)/256, 256, 0, stream>>>(ew1, ew2, cw1, w1x, w1rp, w1cp, w2p, c1p);
    prep_w2<<<(NL*32*128 + NL*16*128 + 16*128 + 16*16 + 255)/256, 256, 0, stream>>>(
        nw1, nw2, ow1, ow2, n1p, n2p, o1p, o2p);
    te_kernel<<<NBATCH, HID, 0, stream>>>(t, tw1, tb1, tw2, tb2, te);
    embed_kernel<<<NN/2, 256, 0, stream>>>(h_in, x_in, batch, node_w, node_b, te, h, hbf, x0, m_i);

    const int NBLK = (NN + NPB - 1) / NPB;   // 782
    const int OBLK = (NN + 63) / 64;         // 391
    float* xc = x0; float* xn = x1;
    for (int i = 0; i < NL; i++) {
        pq_kernel<<<OBLK, 256, 0, stream>>>(
            hbf, w1rp + (size_t)i*16*128*8, w1cp + (size_t)i*16*128*8, Pq, Qq);
        hipMemcpyAsync(xn, xc, (size_t)NN*3*sizeof(float), hipMemcpyDeviceToDevice, stream);
        edge_mfma<<<NEDGE/EPB, 256, 0, stream>>>(
            Pq, Qq, xc, xn, m_i, rowp, colp, eabp,
            w1x + (size_t)i*4*128*8, eb1 + (size_t)i*HID,
            w2p + (size_t)i*16*128*8, eb2 + (size_t)i*HID,
            c1p + (size_t)i*16*128*8, cb1 + (size_t)i*HID,
            attw + (size_t)i*HID, attb + i,
            cw2 + (size_t)i*HID);
        node_mfma<<<NBLK, 256, 0, stream>>>(
            h, hbf, m_i,
            n1p + (size_t)i*32*128*8, nb1 + (size_t)i*HID,
            n2p + (size_t)i*16*128*8, nb2 + (size_t)i*HID,
            lng + (size_t)i*HID,      lnb + (size_t)i*HID);
        float* tmp = xc; xc = xn; xn = tmp;
    }

    out_mfma<<<OBLK, 256, 0, stream>>>(hbf, o1p, ob1, o2p, ob2, hw, hb, (float*)d_out);
}

// Round 12
// 1017.404 us; speedup vs baseline: 1.0630x; 1.0028x over previous
//
#include <hip/hip_runtime.h>
#include <hip/hip_bf16.h>
#include <cmath>

#define NN      25000
#define NEDGE   400000
#define NBATCH  64
#define IN_DIM  16
#define HID     128
#define OUT_DIM 16
#define EDGE_DIM 16
#define TDIM    64
#define NL      4
#define EIN     273
#define EPB     32            // edges per block (MFMA edge kernel)
#define EPAD    33            // e-dimension pad for edge LDS A tiles
#define E3OFF   (16*EPAD*8)   // A3 region offset (elements) inside sA
#define W2KB    16            // k-blocks for 128-K GEMMs
#define A_PAD   65            // e-dimension pad for 64-row LDS A tiles (pq/out)
#define NPB     32            // nodes per block (node kernel)
#define NPAD    33            // e-pad for node kernel

typedef short bfrag __attribute__((ext_vector_type(8)));
typedef float ffrag __attribute__((ext_vector_type(4)));

// fast silu/sigmoid: v_exp + v_rcp (approx) — saves the precise-division sequence
__device__ __forceinline__ float siluf(float v) { return v * __builtin_amdgcn_rcpf(1.f + __expf(-v)); }
__device__ __forceinline__ float sigm(float v)  { return __builtin_amdgcn_rcpf(1.f + __expf(-v)); }
__device__ __forceinline__ unsigned short f2b(float f) {
    unsigned u = __float_as_uint(f);
    u = (u + 0x7FFFu + ((u >> 16) & 1u)) >> 16;
    return (unsigned short)u;
}
__device__ __forceinline__ float b2f(unsigned short b) {
    return __uint_as_float(((unsigned)b) << 16);
}
// interleaved column map: slot n' holds feature ileave(n') so that thread
// (w,colid) owns adjacent features f0=w*32+2*colid (nt=0), f0+1 (nt=1)
__device__ __forceinline__ int ileave(int n) {
    return (n & 0x60) | ((n & 15) << 1) | ((n >> 4) & 1);
}

// ================= sort prep =================
__global__ __launch_bounds__(256) void hist_kernel(const int* __restrict__ row, int* __restrict__ deg) {
    const int tid = blockIdx.x * 256 + threadIdx.x;
    if (tid < NEDGE) atomicAdd(&deg[row[tid]], 1);
}

__global__ __launch_bounds__(1024) void scan_kernel(const int* __restrict__ deg, int* __restrict__ row_start) {
    __shared__ int part[1024];
    const int tid = threadIdx.x;
    const int base = tid * 25;
    int sum = 0;
    for (int i = 0; i < 25; i++) { const int idx = base + i; if (idx < NN) sum += deg[idx]; }
    part[tid] = sum;
    __syncthreads();
    for (int off = 1; off < 1024; off <<= 1) {
        int v = (tid >= off) ? part[tid - off] : 0;
        __syncthreads();
        part[tid] += v;
        __syncthreads();
    }
    int run = part[tid] - sum;
    for (int i = 0; i < 25; i++) {
        const int idx = base + i;
        if (idx < NN) { row_start[idx] = run; run += deg[idx]; }
    }
    if (tid == 1023) row_start[NN] = part[1023];
}

__global__ __launch_bounds__(256) void scatter_kernel(
    const int* __restrict__ row, const int* __restrict__ col,
    const int* __restrict__ row_start, int* __restrict__ cursor,
    int* __restrict__ rowp, int* __restrict__ colp, int* __restrict__ eorder)
{
    const int tid = blockIdx.x * 256 + threadIdx.x;
    if (tid >= NEDGE) return;
    const int r = row[tid];
    const int pos = row_start[r] + atomicAdd(&cursor[r], 1);
    rowp[pos] = r; colp[pos] = col[tid]; eorder[pos] = tid;
}

__global__ __launch_bounds__(256) void ea_pack(
    const float* __restrict__ ea, const int* __restrict__ eorder, unsigned short* __restrict__ eabp)
{
    const int tid = blockIdx.x * 256 + threadIdx.x;
    if (tid >= NEDGE) return;
    const int e = eorder[tid];
    const float4* src = (const float4*)&ea[(size_t)e * 16];
    bfrag o0, o1;
    #pragma unroll
    for (int q = 0; q < 2; q++) {
        const float4 a = src[q];
        o0[q*4+0] = (short)f2b(a.x); o0[q*4+1] = (short)f2b(a.y);
        o0[q*4+2] = (short)f2b(a.z); o0[q*4+3] = (short)f2b(a.w);
    }
    #pragma unroll
    for (int q = 0; q < 2; q++) {
        const float4 a = src[2+q];
        o1[q*4+0] = (short)f2b(a.x); o1[q*4+1] = (short)f2b(a.y);
        o1[q*4+2] = (short)f2b(a.z); o1[q*4+3] = (short)f2b(a.w);
    }
    *(bfrag*)&eabp[(size_t)tid * 16]     = o0;
    *(bfrag*)&eabp[(size_t)tid * 16 + 8] = o1;
}

// ================= prep: edge weights =================
__global__ __launch_bounds__(256) void prep_w(
    const float* __restrict__ ew1, const float* __restrict__ ew2, const float* __restrict__ cw1,
    unsigned short* __restrict__ w1x, unsigned short* __restrict__ w1rp,
    unsigned short* __restrict__ w1cp, unsigned short* __restrict__ w2p,
    unsigned short* __restrict__ c1p)
{
    const int PER_L = 68 * 128;  // 4 + 16 + 16 + 16 + 16 kblocks
    int tid = blockIdx.x * 256 + threadIdx.x;
    if (tid >= NL * PER_L) return;
    const int l = tid / PER_L, rem = tid % PER_L;
    const int kb = rem >> 7, n = rem & 127;
    unsigned short o[8];
    const float* W1 = ew1 + (size_t)l * EIN * HID;
    if (kb < 4) {
        const int nc = ileave(n);
        #pragma unroll
        for (int j = 0; j < 8; j++) {
            const int kk = kb * 8 + j;
            const int ok = (kk < 16) ? (257 + kk) : (kk == 16 ? 256 : -1);
            o[j] = (ok >= 0) ? f2b(W1[(size_t)ok * HID + nc]) : (unsigned short)0;
        }
        #pragma unroll
        for (int j = 0; j < 8; j++) w1x[(((size_t)l * 4 + kb) * 128 + n) * 8 + j] = o[j];
    } else if (kb < 20) {
        const int kb2 = kb - 4;
        const int nc = ileave(n);
        #pragma unroll
        for (int j = 0; j < 8; j++) o[j] = f2b(W1[(size_t)(kb2 * 8 + j) * HID + nc]);
        #pragma unroll
        for (int j = 0; j < 8; j++) w1rp[(((size_t)l * 16 + kb2) * 128 + n) * 8 + j] = o[j];
    } else if (kb < 36) {
        const int kb2 = kb - 20;
        const int nc = ileave(n);
        #pragma unroll
        for (int j = 0; j < 8; j++) o[j] = f2b(W1[(size_t)(128 + kb2 * 8 + j) * HID + nc]);
        #pragma unroll
        for (int j = 0; j < 8; j++) w1cp[(((size_t)l * 16 + kb2) * 128 + n) * 8 + j] = o[j];
    } else if (kb < 52) {
        const int kb2 = kb - 36;
        const float* W = ew2 + (size_t)l * HID * HID;
        const int nc = ileave(n);
        #pragma unroll
        for (int j = 0; j < 8; j++) o[j] = f2b(W[(size_t)(kb2 * 8 + j) * HID + nc]);
        #pragma unroll
        for (int j = 0; j < 8; j++) w2p[(((size_t)l * W2KB + kb2) * 128 + n) * 8 + j] = o[j];
    } else {
        const int kb2 = kb - 52;
        const float* W = cw1 + (size_t)l * HID * HID;
        #pragma unroll
        for (int j = 0; j < 8; j++) o[j] = f2b(W[(size_t)(kb2 * 8 + j) * HID + n]);
        #pragma unroll
        for (int j = 0; j < 8; j++) c1p[(((size_t)l * W2KB + kb2) * 128 + n) * 8 + j] = o[j];
    }
}

// ================= prep: node/out weights =================
__global__ __launch_bounds__(256) void prep_w2(
    const float* __restrict__ nw1, const float* __restrict__ nw2,
    const float* __restrict__ ow1, const float* __restrict__ ow2,
    unsigned short* __restrict__ n1p, unsigned short* __restrict__ n2p,
    unsigned short* __restrict__ o1p, unsigned short* __restrict__ o2p)
{
    const int C1 = NL * 32 * 128;
    const int C2 = C1 + NL * 16 * 128;
    const int C3 = C2 + 16 * 128;
    const int C4 = C3 + 16 * 16;
    int tid = blockIdx.x * 256 + threadIdx.x;
    if (tid >= C4) return;
    if (tid < C1) {
        const int l = tid / (32*128), rem = tid % (32*128);
        const int kb = rem >> 7, n = rem & 127;
        const int nc = ileave(n);
        #pragma unroll
        for (int j = 0; j < 8; j++)
            n1p[(size_t)tid*8 + j] = f2b(nw1[((size_t)l*256 + kb*8 + j)*128 + nc]);
    } else if (tid < C2) {
        const int t2 = tid - C1;
        const int l = t2 / (16*128), rem = t2 % (16*128);
        const int kb = rem >> 7, n = rem & 127;
        const int nc = ileave(n);
        #pragma unroll
        for (int j = 0; j < 8; j++)
            n2p[(size_t)t2*8 + j] = f2b(nw2[((size_t)l*128 + kb*8 + j)*128 + nc]);
    } else if (tid < C3) {
        const int t2 = tid - C2;
        const int kb = t2 >> 7, n = t2 & 127;
        #pragma unroll
        for (int j = 0; j < 8; j++)
            o1p[(size_t)t2*8 + j] = f2b(ow1[(size_t)(kb*8 + j)*128 + n]);
    } else {
        const int t2 = tid - C3;
        const int kb = t2 >> 4, n = t2 & 15;
        #pragma unroll
        for (int j = 0; j < 8; j++)
            o2p[(size_t)t2*8 + j] = f2b(ow2[(size_t)(kb*8 + j)*16 + n]);
    }
}

// ================= time embedding =================
__global__ __launch_bounds__(HID) void te_kernel(
    const float* __restrict__ t, const float* __restrict__ tw1, const float* __restrict__ tb1,
    const float* __restrict__ tw2, const float* __restrict__ tb2, float* __restrict__ te_out)
{
    __shared__ float s0[TDIM];
    __shared__ float s1[HID];
    const int b = blockIdx.x, j = threadIdx.x;
    const float tv = t[b];
    if (j < TDIM) {
        const int k = j & 31;
        const float freq = expf((float)k * (-logf(10000.f) / 31.f));
        const float a = tv * freq;
        s0[j] = (j < 32) ? sinf(a) : cosf(a);
    }
    __syncthreads();
    float acc = tb1[j];
    for (int k = 0; k < TDIM; k++) acc += s0[k] * tw1[k*HID + j];
    s1[j] = siluf(acc);
    __syncthreads();
    float acc2 = tb2[j];
    for (int k = 0; k < HID; k++) acc2 += s1[k] * tw2[k*HID + j];
    te_out[b*HID + j] = acc2;
}

// ================= node embedding: 2 nodes/block; zeroes m_i for layer 0 =================
__global__ __launch_bounds__(256) void embed_kernel(
    const float* __restrict__ h_in, const float* __restrict__ x_in,
    const int* __restrict__ batch,
    const float* __restrict__ node_w, const float* __restrict__ node_b,
    const float* __restrict__ te, float* __restrict__ h, unsigned short* __restrict__ hbf,
    float* __restrict__ x0, float* __restrict__ m_i)
{
    __shared__ float hs[2][IN_DIM];
    const int local = threadIdx.x >> 7;
    const int j = threadIdx.x & 127;
    const int n = blockIdx.x * 2 + local;
    if (j < IN_DIM) hs[local][j] = h_in[n*IN_DIM + j];
    if (j >= 64 && j < 67) x0[n*3 + (j - 64)] = x_in[n*3 + (j - 64)];
    __syncthreads();
    float acc = node_b[j];
    #pragma unroll
    for (int k = 0; k < IN_DIM; k++) acc += hs[local][k] * node_w[k*HID + j];
    acc += te[batch[n]*HID + j];
    h[(size_t)n*HID + j]   = acc;
    hbf[(size_t)n*HID + j] = f2b(acc);
    m_i[(size_t)n*HID + j] = 0.f;
}

// ================= per-layer precompute: P = h@W1row, Q = h@W1col (bf16 out) =================
__global__ __launch_bounds__(256) void pq_kernel(
    const unsigned short* __restrict__ hbf,
    const unsigned short* __restrict__ Wr, const unsigned short* __restrict__ Wc,
    unsigned short* __restrict__ P, unsigned short* __restrict__ Q)
{
    __shared__ unsigned short sA[16 * A_PAD * 8];
    const int t = threadIdx.x, lane = t & 63, w = t >> 6;
    const int quad = lane >> 4, colid = lane & 15;
    const int n0 = blockIdx.x * 64;

    #pragma unroll
    for (int it = 0; it < 4; it++) {
        const int c = t + it * 256;
        const int e = c >> 4, kb = c & 15;
        const int nidx = min(n0 + e, NN - 1);
        *(bfrag*)&sA[(kb*A_PAD + e) * 8] = *(const bfrag*)&hbf[(size_t)nidx * HID + kb * 8];
    }
    __syncthreads();

    ffrag aP[4][2] = {}, aQ[4][2] = {};
    for (int ks = 0; ks < 4; ks++) {
        const int kb = ks * 4 + quad;
        const bfrag p0 = *(const bfrag*)&Wr[((size_t)kb * 128 + w*32 + colid) * 8];
        const bfrag p1 = *(const bfrag*)&Wr[((size_t)kb * 128 + w*32 + 16 + colid) * 8];
        const bfrag q0 = *(const bfrag*)&Wc[((size_t)kb * 128 + w*32 + colid) * 8];
        const bfrag q1 = *(const bfrag*)&Wc[((size_t)kb * 128 + w*32 + 16 + colid) * 8];
        #pragma unroll
        for (int mt = 0; mt < 4; mt++) {
            const bfrag a = *(const bfrag*)&sA[(kb*A_PAD + mt*16 + colid) * 8];
            aP[mt][0] = __builtin_amdgcn_mfma_f32_16x16x32_bf16(a, p0, aP[mt][0], 0, 0, 0);
            aP[mt][1] = __builtin_amdgcn_mfma_f32_16x16x32_bf16(a, p1, aP[mt][1], 0, 0, 0);
            aQ[mt][0] = __builtin_amdgcn_mfma_f32_16x16x32_bf16(a, q0, aQ[mt][0], 0, 0, 0);
            aQ[mt][1] = __builtin_amdgcn_mfma_f32_16x16x32_bf16(a, q1, aQ[mt][1], 0, 0, 0);
        }
    }
    const int f0 = w*32 + 2*colid;
    #pragma unroll
    for (int mt = 0; mt < 4; mt++)
        #pragma unroll
        for (int reg = 0; reg < 4; reg++) {
            const int n = n0 + mt*16 + quad*4 + reg;
            if (n < NN) {
                *(__hip_bfloat162*)&P[(size_t)n*HID + f0] =
                    __float22bfloat162_rn(make_float2(aP[mt][0][reg], aP[mt][1][reg]));
                *(__hip_bfloat162*)&Q[(size_t)n*HID + f0] =
                    __float22bfloat162_rn(make_float2(aQ[mt][0][reg], aQ[mt][1][reg]));
            }
        }
}

// ================= fused MFMA edge kernel (row-sorted edges; 32 edges/block) =================
__global__ __launch_bounds__(256) void edge_mfma(
    const unsigned short* __restrict__ P, const unsigned short* __restrict__ Q,
    const float* __restrict__ x,
    float* __restrict__ x_new, float* __restrict__ m_i,
    const int* __restrict__ rowp, const int* __restrict__ colp,
    const unsigned short* __restrict__ eabp,
    const unsigned short* __restrict__ W1X, const float* __restrict__ B1,
    const unsigned short* __restrict__ W2p, const float* __restrict__ B2,
    const unsigned short* __restrict__ C1p, const float* __restrict__ CB1,
    const float* __restrict__ AW, const float* __restrict__ ABv,
    const float* __restrict__ CW2)
{
    __shared__ unsigned short sA[32 * EPAD * 8];  // A2 = kb0..15; A3 at E3OFF (Aea aliases A3)
    __shared__ int rc[EPB][2];
    __shared__ float AWs[HID];
    float* scr  = (float*)sA;       // aliases dead A2 region during epilogues
    float* attS = scr;              // [32]
    float* pscr = scr;              // [64 k][34] coord partials; alive only after final sync

    const int t = threadIdx.x;
    const int e0 = blockIdx.x * EPB;
    const int lane = t & 63, w = t >> 6;
    const int quad = lane >> 4, colid = lane & 15;
    const int f0 = w*32 + 2*colid;

    // ---- stage: rc, coord-diff, ea + radial into Aea (A3 region), AW ----
    float cd0 = 0.f, cd1 = 0.f, cd2 = 0.f;
    if (t < EPB) {
        const int r = rowp[e0 + t], c = colp[e0 + t];
        rc[t][0] = r; rc[t][1] = c;
        const float dx = x[r*3+0] - x[c*3+0];
        const float dy = x[r*3+1] - x[c*3+1];
        const float dz = x[r*3+2] - x[c*3+2];
        const float rad = dx*dx + dy*dy + dz*dz;
        const float inv = 1.f / sqrtf(rad + 1e-8f);
        cd0 = dx*inv; cd1 = dy*inv; cd2 = dz*inv;
        unsigned short* p2 = &sA[E3OFF + (2*EPAD + t) * 8];   // Aea kb2: [radial, 0..]
        p2[0] = f2b(rad);
        #pragma unroll
        for (int j = 1; j < 8; j++) p2[j] = 0;
        unsigned short* p3 = &sA[E3OFF + (3*EPAD + t) * 8];   // Aea kb3: zeros
        #pragma unroll
        for (int j = 0; j < 8; j++) p3[j] = 0;
    }
    if (t >= 128 && t < 256) AWs[t - 128] = AW[t - 128];
    if (t < 64) {
        const int e = t >> 1, hh = t & 1;
        *(bfrag*)&sA[E3OFF + (hh*EPAD + e) * 8] = *(const bfrag*)&eabp[(size_t)(e0 + e) * 16 + hh * 8];
    }
    __syncthreads();

    // ---- PREFETCH: issue all 16 P/Q gathers now (bf16 u32, covers f0,f0+1) ----
    unsigned pv[8], qv[8];
    #pragma unroll
    for (int i = 0; i < 8; i++) {
        const int e = (i >> 2)*16 + quad*4 + (i & 3);   // [mt][reg] order, mt 0..1
        pv[i] = *(const unsigned*)&P[(size_t)rc[e][0]*HID + f0];
        qv[i] = *(const unsigned*)&Q[(size_t)rc[e][1]*HID + f0];
    }

    // ---- GEMM_ea: [32 x 32] @ [32 x 128] (K=32: ea|radial), bias B1 preloaded ----
    ffrag accea[2][2];
    {
        const float b0v = B1[f0], b1v = B1[f0+1];
        #pragma unroll
        for (int mt = 0; mt < 2; mt++)
            #pragma unroll
            for (int r = 0; r < 4; r++) { accea[mt][0][r] = b0v; accea[mt][1][r] = b1v; }
    }
    {
        const bfrag eb0 = *(const bfrag*)&W1X[((size_t)quad * 128 + w*32 + colid) * 8];
        const bfrag eb1 = *(const bfrag*)&W1X[((size_t)quad * 128 + w*32 + 16 + colid) * 8];
        #pragma unroll
        for (int mt = 0; mt < 2; mt++) {
            const bfrag a = *(const bfrag*)&sA[E3OFF + (quad*EPAD + mt*16 + colid) * 8];
            accea[mt][0] = __builtin_amdgcn_mfma_f32_16x16x32_bf16(a, eb0, accea[mt][0], 0, 0, 0);
            accea[mt][1] = __builtin_amdgcn_mfma_f32_16x16x32_bf16(a, eb1, accea[mt][1], 0, 0, 0);
        }
    }

    // ---- epilogue 1: m1 = silu(P[row] + Q[col] + ea_part), packed bf16x2 -> A2 ----
    {
        const int kb = f0 >> 3, j = f0 & 7;
        #pragma unroll
        for (int mt = 0; mt < 2; mt++)
            #pragma unroll
            for (int reg = 0; reg < 4; reg++) {
                const int i = mt*4 + reg;
                const int e = mt*16 + quad*4 + reg;
                const float v0 = siluf(__uint_as_float(pv[i] << 16)
                                     + __uint_as_float(qv[i] << 16) + accea[mt][0][reg]);
                const float v1 = siluf(__uint_as_float(pv[i] & 0xFFFF0000u)
                                     + __uint_as_float(qv[i] & 0xFFFF0000u) + accea[mt][1][reg]);
                *(__hip_bfloat162*)&sA[(kb*EPAD + e) * 8 + j] =
                    __float22bfloat162_rn(make_float2(v0, v1));   // A2
            }
    }
    __syncthreads();

    // ---- GEMM2: [32 x 128] @ [128 x 128] (interleaved columns) ----
    ffrag acc2[2][2] = {};
    for (int ks = 0; ks < 4; ks++) {
        const int kb = ks * 4 + quad;
        const bfrag b0 = *(const bfrag*)&W2p[((size_t)kb * 128 + w*32 + colid) * 8];
        const bfrag b1 = *(const bfrag*)&W2p[((size_t)kb * 128 + w*32 + 16 + colid) * 8];
        #pragma unroll
        for (int mt = 0; mt < 2; mt++) {
            const bfrag a = *(const bfrag*)&sA[(kb*EPAD + mt*16 + colid) * 8];
            acc2[mt][0] = __builtin_amdgcn_mfma_f32_16x16x32_bf16(a, b0, acc2[mt][0], 0, 0, 0);
            acc2[mt][1] = __builtin_amdgcn_mfma_f32_16x16x32_bf16(a, b1, acc2[mt][1], 0, 0, 0);
        }
    }
    // ---- epilogue 2: silu -> packed bf16x2 UNSCALED m2 into A3 ----
    {
        const int kb = f0 >> 3, j = f0 & 7;
        const float b0v = B2[f0], b1v = B2[f0+1];
        #pragma unroll
        for (int mt = 0; mt < 2; mt++)
            #pragma unroll
            for (int reg = 0; reg < 4; reg++) {
                const float v0 = siluf(acc2[mt][0][reg] + b0v);
                const float v1 = siluf(acc2[mt][1][reg] + b1v);
                const int e = mt*16 + quad*4 + reg;
                *(__hip_bfloat162*)&sA[E3OFF + (kb*EPAD + e) * 8 + j] =
                    __float22bfloat162_rn(make_float2(v0, v1));
            }
    }
    __syncthreads();   // A3 visible; A2 dead (scr region safe)

    // ---- attention: att[e] = sigmoid(m2[e] . AW + ab); 8 lanes per edge ----
    {
        const int e = t >> 3, q = t & 7;
        float s = 0.f;
        #pragma unroll
        for (int kk = 0; kk < 2; kk++) {
            const int kb = q*2 + kk;
            const bfrag v = *(const bfrag*)&sA[E3OFF + (kb*EPAD + e) * 8];
            #pragma unroll
            for (int j = 0; j < 8; j++) s += b2f((unsigned short)v[j]) * AWs[kb*8 + j];
        }
        s += __shfl_xor(s, 1);
        s += __shfl_xor(s, 2);
        s += __shfl_xor(s, 4);
        if (q == 0) attS[e] = sigm(s + ABv[0]);
    }
    __syncthreads();

    // ---- GEMM3 on UNSCALED m2: [32 x 128] @ CW1 [128 x 128] (canonical cols) ----
    ffrag acc3[2][2] = {};
    for (int ks = 0; ks < 4; ks++) {
        const int kb = ks * 4 + quad;
        const bfrag b0 = *(const bfrag*)&C1p[((size_t)kb * 128 + w*32 + colid) * 8];
        const bfrag b1 = *(const bfrag*)&C1p[((size_t)kb * 128 + w*32 + 16 + colid) * 8];
        #pragma unroll
        for (int mt = 0; mt < 2; mt++) {
            const bfrag a = *(const bfrag*)&sA[E3OFF + (kb*EPAD + mt*16 + colid) * 8];
            acc3[mt][0] = __builtin_amdgcn_mfma_f32_16x16x32_bf16(a, b0, acc3[mt][0], 0, 0, 0);
            acc3[mt][1] = __builtin_amdgcn_mfma_f32_16x16x32_bf16(a, b1, acc3[mt][1], 0, 0, 0);
        }
    }

    // ---- m_i segmented reduction: READ-ONLY, scaled on the fly; 8 edges per wave ----
    {
        const int fkb0 = lane >> 3,     fj = lane & 7;     // f = lane
        const int fkb1 = 8 + (lane >> 3);                   // f = lane + 64
        float a0 = 0.f, a1 = 0.f;
        for (int i = 0; i < 8; i++) {
            const int e = (w << 3) + i;
            const float av = attS[e];
            const int r = rc[e][0];
            a0 += b2f(sA[E3OFF + (fkb0*EPAD + e) * 8 + fj]) * av;
            a1 += b2f(sA[E3OFF + (fkb1*EPAD + e) * 8 + fj]) * av;
            const bool flush = (i == 7) || (rc[e+1][0] != r);
            if (flush) {
                atomicAdd(&m_i[(size_t)r * HID + lane],      a0);
                atomicAdd(&m_i[(size_t)r * HID + lane + 64], a1);
                a0 = 0.f; a1 = 0.f;
            }
        }
    }

    // ---- GEMM3 epilogue: att applied here (row-scaling commutes), coord partials ----
    float p[2][4];
    {
        const float cb0v = CB1[w*32 + colid], cb1v = CB1[w*32 + 16 + colid];
        const float cwv0 = CW2[w*32 + colid], cwv1 = CW2[w*32 + 16 + colid];
        #pragma unroll
        for (int mt = 0; mt < 2; mt++) {
            const float4 a4 = *(const float4*)&attS[mt*16 + quad*4];
            const float att_r[4] = {a4.x, a4.y, a4.z, a4.w};
            #pragma unroll
            for (int reg = 0; reg < 4; reg++)
                p[mt][reg] = siluf(att_r[reg] * acc3[mt][0][reg] + cb0v) * cwv0
                           + siluf(att_r[reg] * acc3[mt][1][reg] + cb1v) * cwv1;
        }
    }
    __syncthreads();   // all A3/attS reads done; pscr may now overwrite A2/A3
    // scatter: pscr[k][e] stride 34 (even -> b64-aligned float2 writes, ~2-way banks)
    {
        const int k = w*16 + colid;
        #pragma unroll
        for (int mt = 0; mt < 2; mt++)
            #pragma unroll
            for (int rr = 0; rr < 2; rr++) {
                const int e = mt*16 + quad*4 + rr*2;
                *(float2*)&pscr[k*34 + e] = make_float2(p[mt][rr*2], p[mt][rr*2+1]);
            }
    }
    __syncthreads();
    if (t < EPB) {
        float s = 0.f;
        #pragma unroll
        for (int k2 = 0; k2 < 64; k2++) s += pscr[k2*34 + t];
        const int r = rc[t][0];
        atomicAdd(&x_new[r*3+0], cd0 * s);
        atomicAdd(&x_new[r*3+1], cd1 * s);
        atomicAdd(&x_new[r*3+2], cd2 * s);
    }
}

// ================= MFMA node MLP + residual + layernorm (32 nodes/block); zeroes m_i =================
__global__ __launch_bounds__(256) void node_mfma(
    float* __restrict__ h, unsigned short* __restrict__ hbf, float* __restrict__ m_i,
    const unsigned short* __restrict__ N1p, const float* __restrict__ NB1,
    const unsigned short* __restrict__ N2p, const float* __restrict__ NB2,
    const float* __restrict__ LG, const float* __restrict__ LB)
{
    __shared__ unsigned short sA[32 * NPAD * 8];
    __shared__ float mu_s[NPB], rs_s[NPB];
    float* hres = (float*)sA;                       // [32][130] fp32

    const int t = threadIdx.x, lane = t & 63, w = t >> 6;
    const int quad = lane >> 4, colid = lane & 15;
    const int n0 = blockIdx.x * NPB;

    #pragma unroll
    for (int it = 0; it < 2; it++) {
        const int c = t + it * 256;
        const int e = c >> 4, kb = c & 15;
        const int nidx = min(n0 + e, NN - 1);
        *(bfrag*)&sA[(kb*NPAD + e) * 8] = *(const bfrag*)&hbf[(size_t)nidx * HID + kb * 8];
    }
    #pragma unroll
    for (int it = 0; it < 2; it++) {
        const int c = t + it * 256;
        const int e = c >> 4, kb = c & 15;
        const int nidx = min(n0 + e, NN - 1);
        const float4 v0 = *(const float4*)&m_i[(size_t)nidx * HID + kb * 8];
        const float4 v1 = *(const float4*)&m_i[(size_t)nidx * HID + kb * 8 + 4];
        bfrag bv;
        bv[0]=(short)f2b(v0.x); bv[1]=(short)f2b(v0.y); bv[2]=(short)f2b(v0.z); bv[3]=(short)f2b(v0.w);
        bv[4]=(short)f2b(v1.x); bv[5]=(short)f2b(v1.y); bv[6]=(short)f2b(v1.z); bv[7]=(short)f2b(v1.w);
        *(bfrag*)&sA[((16 + kb)*NPAD + e) * 8] = bv;
        if (n0 + e < NN) {
            const float4 z4 = {0.f, 0.f, 0.f, 0.f};
            *(float4*)&m_i[(size_t)nidx * HID + kb * 8]     = z4;
            *(float4*)&m_i[(size_t)nidx * HID + kb * 8 + 4] = z4;
        }
    }
    __syncthreads();

    const int f0 = w*32 + 2*colid;
    ffrag acc1[2][2];
    {
        const float b0v = NB1[f0], b1v = NB1[f0+1];
        #pragma unroll
        for (int mt = 0; mt < 2; mt++)
            #pragma unroll
            for (int r = 0; r < 4; r++) { acc1[mt][0][r] = b0v; acc1[mt][1][r] = b1v; }
    }
    for (int ks = 0; ks < 8; ks++) {
        const int kb = ks * 4 + quad;
        const bfrag b0 = *(const bfrag*)&N1p[((size_t)kb * 128 + w*32 + colid) * 8];
        const bfrag b1 = *(const bfrag*)&N1p[((size_t)kb * 128 + w*32 + 16 + colid) * 8];
        #pragma unroll
        for (int mt = 0; mt < 2; mt++) {
            const bfrag a = *(const bfrag*)&sA[(kb*NPAD + mt*16 + colid) * 8];
            acc1[mt][0] = __builtin_amdgcn_mfma_f32_16x16x32_bf16(a, b0, acc1[mt][0], 0, 0, 0);
            acc1[mt][1] = __builtin_amdgcn_mfma_f32_16x16x32_bf16(a, b1, acc1[mt][1], 0, 0, 0);
        }
    }
    __syncthreads();
    {
        const int kb = f0 >> 3, j = f0 & 7;
        #pragma unroll
        for (int mt = 0; mt < 2; mt++)
            #pragma unroll
            for (int reg = 0; reg < 4; reg++) {
                const float v0 = siluf(acc1[mt][0][reg]);
                const float v1 = siluf(acc1[mt][1][reg]);
                const int e = mt*16 + quad*4 + reg;
                *(__hip_bfloat162*)&sA[(kb*NPAD + e) * 8 + j] =
                    __float22bfloat162_rn(make_float2(v0, v1));
            }
    }
    __syncthreads();

    ffrag acc2[2][2];
    {
        const float b0v = NB2[f0], b1v = NB2[f0+1];
        #pragma unroll
        for (int mt = 0; mt < 2; mt++)
            #pragma unroll
            for (int r = 0; r < 4; r++) { acc2[mt][0][r] = b0v; acc2[mt][1][r] = b1v; }
    }
    for (int ks = 0; ks < 4; ks++) {
        const int kb = ks * 4 + quad;
        const bfrag b0 = *(const bfrag*)&N2p[((size_t)kb * 128 + w*32 + colid) * 8];
        const bfrag b1 = *(const bfrag*)&N2p[((size_t)kb * 128 + w*32 + 16 + colid) * 8];
        #pragma unroll
        for (int mt = 0; mt < 2; mt++) {
            const bfrag a = *(const bfrag*)&sA[(kb*NPAD + mt*16 + colid) * 8];
            acc2[mt][0] = __builtin_amdgcn_mfma_f32_16x16x32_bf16(a, b0, acc2[mt][0], 0, 0, 0);
            acc2[mt][1] = __builtin_amdgcn_mfma_f32_16x16x32_bf16(a, b1, acc2[mt][1], 0, 0, 0);
        }
    }
    __syncthreads();
    {
        #pragma unroll
        for (int mt = 0; mt < 2; mt++)
            #pragma unroll
            for (int reg = 0; reg < 4; reg++) {
                const int row = mt*16 + quad*4 + reg;
                const int nidx = min(n0 + row, NN - 1);
                const float2 hr = *(const float2*)&h[(size_t)nidx*HID + f0];
                float2 o;
                o.x = acc2[mt][0][reg] + hr.x;
                o.y = acc2[mt][1][reg] + hr.y;
                *(float2*)&hres[row*130 + f0] = o;
            }
    }
    __syncthreads();
    {
        const int row = t >> 3, q = t & 7;
        float s = 0.f, s2 = 0.f;
        #pragma unroll
        for (int i = 0; i < 16; i++) {
            const float v = hres[row*130 + q*16 + i];
            s += v; s2 += v*v;
        }
        s += __shfl_xor(s, 1); s2 += __shfl_xor(s2, 1);
        s += __shfl_xor(s, 2); s2 += __shfl_xor(s2, 2);
        s += __shfl_xor(s, 4); s2 += __shfl_xor(s2, 4);
        if (q == 0) {
            const float mu = s * (1.f/HID);
            mu_s[row] = mu;
            rs_s[row] = rsqrtf(s2 * (1.f/HID) - mu*mu + 1e-5f);
        }
    }
    __syncthreads();
    for (int idx = t; idx < NPB*HID; idx += 256) {
        const int row = idx >> 7, f = idx & 127;
        const int n = n0 + row;
        if (n < NN) {
            const float v = (hres[row*130 + f] - mu_s[row]) * rs_s[row] * LG[f] + LB[f];
            h[(size_t)n*HID + f]   = v;
            hbf[(size_t)n*HID + f] = f2b(v);
        }
    }
}

// ================= MFMA output heads =================
__global__ __launch_bounds__(256) void out_mfma(
    const unsigned short* __restrict__ hbf,
    const unsigned short* __restrict__ O1p, const float* __restrict__ OB1,
    const unsigned short* __restrict__ O2p, const float* __restrict__ OB2,
    const float* __restrict__ HW, const float* __restrict__ HB,
    float* __restrict__ out)
{
    __shared__ unsigned short sA[32 * A_PAD * 8];
    __shared__ float hws[HID*3];
    const int A2O = 16 * A_PAD * 8;

    const int t = threadIdx.x, lane = t & 63, w = t >> 6;
    const int quad = lane >> 4, colid = lane & 15;
    const int n0 = blockIdx.x * 64;

    if (t < 128)      { hws[t] = HW[t]; hws[t+128] = HW[t+128]; }
    else if (t < 256) { const int i = t - 128 + 256; if (i < 384) hws[i] = HW[i]; }
    #pragma unroll
    for (int it = 0; it < 4; it++) {
        const int c = t + it * 256;
        const int e = c >> 4, kb = c & 15;
        const int nidx = min(n0 + e, NN - 1);
        *(bfrag*)&sA[(kb*A_PAD + e) * 8] = *(const bfrag*)&hbf[(size_t)nidx * HID + kb * 8];
    }
    __syncthreads();

    ffrag acc1[4][2];
    {
        const float b0v = OB1[w*32 + colid], b1v = OB1[w*32 + 16 + colid];
        #pragma unroll
        for (int mt = 0; mt < 4; mt++)
            #pragma unroll
            for (int r = 0; r < 4; r++) { acc1[mt][0][r] = b0v; acc1[mt][1][r] = b1v; }
    }
    for (int ks = 0; ks < 4; ks++) {
        const int kb = ks * 4 + quad;
        const bfrag b0 = *(const bfrag*)&O1p[((size_t)kb * 128 + w*32 + colid) * 8];
        const bfrag b1 = *(const bfrag*)&O1p[((size_t)kb * 128 + w*32 + 16 + colid) * 8];
        #pragma unroll
        for (int mt = 0; mt < 4; mt++) {
            const bfrag a = *(const bfrag*)&sA[(kb*A_PAD + mt*16 + colid) * 8];
            acc1[mt][0] = __builtin_amdgcn_mfma_f32_16x16x32_bf16(a, b0, acc1[mt][0], 0, 0, 0);
            acc1[mt][1] = __builtin_amdgcn_mfma_f32_16x16x32_bf16(a, b1, acc1[mt][1], 0, 0, 0);
        }
    }
    {
        #pragma unroll
        for (int mt = 0; mt < 4; mt++)
            #pragma unroll
            for (int nt = 0; nt < 2; nt++) {
                const int f = w*32 + nt*16 + colid;
                const int kb = f >> 3, j = f & 7;
                #pragma unroll
                for (int reg = 0; reg < 4; reg++) {
                    const float v = siluf(acc1[mt][nt][reg]);
                    const int e = mt*16 + quad*4 + reg;
                    sA[A2O + (kb*A_PAD + e) * 8 + j] = f2b(v);
                }
            }
    }
    __syncthreads();

    ffrag acco;
    {
        const float ob2v = OB2[colid];
        #pragma unroll
        for (int r = 0; r < 4; r++) acco[r] = ob2v;
    }
    for (int ks = 0; ks < 4; ks++) {
        const int kb = ks * 4 + quad;
        const bfrag a = *(const bfrag*)&sA[A2O + (kb*A_PAD + w*16 + colid) * 8];
        const bfrag b = *(const bfrag*)&O2p[((size_t)kb * 16 + colid) * 8];
        acco = __builtin_amdgcn_mfma_f32_16x16x32_bf16(a, b, acco, 0, 0, 0);
    }
    #pragma unroll
    for (int reg = 0; reg < 4; reg++) {
        const int rowg = w*16 + quad*4 + reg;
        const int n = n0 + rowg;
        if (n < NN) out[(size_t)n*OUT_DIM + colid] = acco[reg];
    }

    {
        const int rloc = t >> 2, q = t & 3;
        float s0 = 0.f, s1 = 0.f, s2 = 0.f;
        #pragma unroll
        for (int kk = 0; kk < 4; kk++) {
            const int kb = q*4 + kk;
            const bfrag v = *(const bfrag*)&sA[(kb*A_PAD + rloc) * 8];
            #pragma unroll
            for (int j = 0; j < 8; j++) {
                const float hv = b2f((unsigned short)v[j]);
                const int k = kb*8 + j;
                s0 += hv * hws[k*3+0]; s1 += hv * hws[k*3+1]; s2 += hv * hws[k*3+2];
            }
        }
        s0 += __shfl_xor(s0, 1); s1 += __shfl_xor(s1, 1); s2 += __shfl_xor(s2, 1);
        s0 += __shfl_xor(s0, 2); s1 += __shfl_xor(s1, 2); s2 += __shfl_xor(s2, 2);
        const int n = n0 + rloc;
        if (q == 0 && n < NN) {
            out[(size_t)NN*OUT_DIM + n*3 + 0] = s0 + HB[0];
            out[(size_t)NN*OUT_DIM + n*3 + 1] = s1 + HB[1];
            out[(size_t)NN*OUT_DIM + n*3 + 2] = s2 + HB[2];
        }
    }
}

extern "C" void kernel_launch(void* const* d_in, const int* in_sizes, int n_in,
                              void* d_out, int out_size, void* d_ws, size_t ws_size,
                              hipStream_t stream) {
    (void)in_sizes; (void)n_in; (void)out_size; (void)ws_size;
    const float* h_in      = (const float*)d_in[0];
    const float* x_in      = (const float*)d_in[1];
    const int*   edge_idx  = (const int*)  d_in[2];
    const float* t         = (const float*)d_in[3];
    const float* edge_attr = (const float*)d_in[4];
    const int*   batch     = (const int*)  d_in[5];
    const float* node_w = (const float*)d_in[6];
    const float* node_b = (const float*)d_in[7];
    const float* tw1    = (const float*)d_in[8];
    const float* tb1    = (const float*)d_in[9];
    const float* tw2    = (const float*)d_in[10];
    const float* tb2    = (const float*)d_in[11];
    const float* ew1    = (const float*)d_in[12];
    const float* eb1    = (const float*)d_in[13];
    const float* ew2    = (const float*)d_in[14];
    const float* eb2    = (const float*)d_in[15];
    const float* attw   = (const float*)d_in[16];
    const float* attb   = (const float*)d_in[17];
    const float* cw1    = (const float*)d_in[18];
    const float* cb1    = (const float*)d_in[19];
    const float* cw2    = (const float*)d_in[20];
    const float* nw1    = (const float*)d_in[21];
    const float* nb1    = (const float*)d_in[22];
    const float* nw2    = (const float*)d_in[23];
    const float* nb2    = (const float*)d_in[24];
    const float* lng    = (const float*)d_in[25];
    const float* lnb    = (const float*)d_in[26];
    const float* ow1    = (const float*)d_in[27];
    const float* ob1    = (const float*)d_in[28];
    const float* ow2    = (const float*)d_in[29];
    const float* ob2    = (const float*)d_in[30];
    const float* hw     = (const float*)d_in[31];
    const float* hb     = (const float*)d_in[32];

    const int* row = edge_idx;
    const int* col = edge_idx + NEDGE;

    float* ws  = (float*)d_ws;
    float* te  = ws;
    float* h   = te  + NBATCH*HID;
    float* m_i = h   + (size_t)NN*HID;
    float* x0  = m_i + (size_t)NN*HID;
    float* x1  = x0  + NN*3;
    unsigned short* hbf  = (unsigned short*)(x1 + NN*3);
    unsigned short* eabp = hbf + (size_t)NN*HID;
    unsigned short* w1x  = eabp + (size_t)NEDGE*EDGE_DIM;  // NL*4*128*8
    unsigned short* w1rp = w1x  + (size_t)NL*4*128*8;      // NL*16*128*8
    unsigned short* w1cp = w1rp + (size_t)NL*16*128*8;     // NL*16*128*8
    unsigned short* w2p  = w1cp + (size_t)NL*16*128*8;     // NL*16*128*8
    unsigned short* c1p  = w2p  + (size_t)NL*16*128*8;     // NL*16*128*8
    unsigned short* n1p  = c1p  + (size_t)NL*16*128*8;     // NL*32*128*8
    unsigned short* n2p  = n1p  + (size_t)NL*32*128*8;     // NL*16*128*8
    unsigned short* o1p  = n2p  + (size_t)NL*16*128*8;     // 16*128*8
    unsigned short* o2p  = o1p  + (size_t)16*128*8;        // 16*16*8
    unsigned short* Pq   = o2p  + (size_t)16*16*8;         // NN*128 bf16
    unsigned short* Qq   = Pq   + (size_t)NN*HID;          // NN*128 bf16
    int* deg       = (int*)(Qq + (size_t)NN*HID);
    int* row_start = deg + NN;
    int* cursor    = row_start + NN + 1;
    int* rowp      = cursor + NN;
    int* colp      = rowp + NEDGE;
    int* eorder    = colp + NEDGE;

    // ---- edge sort (counting sort by row) ----
    hipMemsetAsync(deg, 0, NN*sizeof(int), stream);
    hipMemsetAsync(cursor, 0, NN*sizeof(int), stream);
    hist_kernel<<<(NEDGE+255)/256, 256, 0, stream>>>(row, deg);
    scan_kernel<<<1, 1024, 0, stream>>>(deg, row_start);
    scatter_kernel<<<(NEDGE+255)/256, 256, 0, stream>>>(row, col, row_start, cursor, rowp, colp, eorder);
    ea_pack<<<(NEDGE+255)/256, 256, 0, stream>>>(edge_attr, eorder, eabp);

    // ---- weight packs + embeddings ----
    prep_w<<<(NL*68*128 + 255)/256, 256, 0, stream>>>(ew1, ew2, cw1, w1x, w1rp, w1cp, w2p, c1p);
    prep_w2<<<(NL*32*128 + NL*16*128 + 16*128 + 16*16 + 255)/256, 256, 0, stream>>>(
        nw1, nw2, ow1, ow2, n1p, n2p, o1p, o2p);
    te_kernel<<<NBATCH, HID, 0, stream>>>(t, tw1, tb1, tw2, tb2, te);
    embed_kernel<<<NN/2, 256, 0, stream>>>(h_in, x_in, batch, node_w, node_b, te, h, hbf, x0, m_i);

    const int NBLK = (NN + NPB - 1) / NPB;   // 782
    const int OBLK = (NN + 63) / 64;         // 391
    float* xc = x0; float* xn = x1;
    for (int i = 0; i < NL; i++) {
        pq_kernel<<<OBLK, 256, 0, stream>>>(
            hbf, w1rp + (size_t)i*16*128*8, w1cp + (size_t)i*16*128*8, Pq, Qq);
        hipMemcpyAsync(xn, xc, (size_t)NN*3*sizeof(float), hipMemcpyDeviceToDevice, stream);
        edge_mfma<<<NEDGE/EPB, 256, 0, stream>>>(
            Pq, Qq, xc, xn, m_i, rowp, colp, eabp,
            w1x + (size_t)i*4*128*8, eb1 + (size_t)i*HID,
            w2p + (size_t)i*16*128*8, eb2 + (size_t)i*HID,
            c1p + (size_t)i*16*128*8, cb1 + (size_t)i*HID,
            attw + (size_t)i*HID, attb + i,
            cw2 + (size_t)i*HID);
        node_mfma<<<NBLK, 256, 0, stream>>>(
            h, hbf, m_i,
            n1p + (size_t)i*32*128*8, nb1 + (size_t)i*HID,
            n2p + (size_t)i*16*128*8, nb2 + (size_t)i*HID,
            lng + (size_t)i*HID,      lnb + (size_t)i*HID);
        float* tmp = xc; xc = xn; xn = tmp;
    }

    out_mfma<<<OBLK, 256, 0, stream>>>(hbf, o1p, ob1, o2p, ob2, hw, hb, (float*)d_out);
}